// Round 5
// baseline (595.176 us; speedup 1.0000x reference)
//
#include <hip/hip_runtime.h>
#include <stdint.h>

// VectorQuantizer: z[32768,512] f32, weight[8192,512] f32 ->
//   out[0 .. 32768*512) = z_q = weight[argmin_k ||z-e_k||^2]  (exact fp32 rows)
//   out[32768*512]      = perplexity
//
// Pipeline:
//  1) k_prep_z: bf16(-2z); k_prep_w: bf16(w) + exact f32 row norms c_k
//  2) k_phase1: 128x128-tile 4-wave bf16 MFMA, double-buffered LDS with
//     counted vmcnt(8) (T3-minimum schedule, 2 raw barriers/step, no drains).
//     acc init = c_k, accumulate (-2z).e -> d = c - 2 z.e directly.
//     Per token keep top-2 packed keys (quantized d | 13-bit code) per
//     128 cells (cell = (split,wc,col), 64 codes each) -> slotbuf
//  3) k_select: global min; margin candidates re-ranked with exact f64 dots
//     (cells with both entries in margin fully rescanned); idx + histogram
//  4) k_gather: z_q rows ; k_perp: perplexity
//
// ws layout (bytes): zb@0 32MB | wb@33554432 8MB | cnorm@41943040 32KB |
//   slot@41975808 32MB | idx@75530240 128KB | counts@75661312 32KB

#define NTOK 32768
#define NE   8192
#define DIM  512
#define MARGIN 4.0f

typedef __attribute__((ext_vector_type(8))) short bf16x8;
typedef __attribute__((ext_vector_type(4))) float f32x4;

#define SBAR   __builtin_amdgcn_s_barrier()
#define SCHED0 __builtin_amdgcn_sched_barrier(0)

__device__ __forceinline__ unsigned int f2bf1(float x) {
  unsigned int u = __float_as_uint(x);
  return (u + 0x7FFFu + ((u >> 16) & 1u)) >> 16;
}
__device__ __forceinline__ unsigned int packbf2(float lo, float hi) {
  return f2bf1(lo) | (f2bf1(hi) << 16);
}

__device__ __forceinline__ void gl_lds16(const void* g, void* l) {
  __builtin_amdgcn_global_load_lds(
      (const __attribute__((address_space(1))) void*)g,
      (__attribute__((address_space(3))) void*)l, 16, 0, 0);
}

__global__ void k_prep_z(const float* __restrict__ z, unsigned int* __restrict__ zb) {
  int i = blockIdx.x * 256 + threadIdx.x;  // one thread per 8 floats
  const float4* zp = (const float4*)z + (size_t)i * 2;
  float4 a = zp[0], b = zp[1];
  uint4 o;  // store bf16(-2z): exact 2x scaling, same rounding as bf16(z)
  o.x = packbf2(-2.f * a.x, -2.f * a.y); o.y = packbf2(-2.f * a.z, -2.f * a.w);
  o.z = packbf2(-2.f * b.x, -2.f * b.y); o.w = packbf2(-2.f * b.z, -2.f * b.w);
  ((uint4*)zb)[i] = o;
}

__global__ void k_prep_w(const float* __restrict__ w, unsigned int* __restrict__ wb,
                         float* __restrict__ cnorm) {
  int row  = blockIdx.x * 4 + (threadIdx.x >> 6);  // one wave per code row
  int lane = threadIdx.x & 63;
  const float4* wp = (const float4*)(w + (size_t)row * DIM) + lane * 2;
  float4 a = wp[0], b = wp[1];
  uint4 o;
  o.x = packbf2(a.x, a.y); o.y = packbf2(a.z, a.w);
  o.z = packbf2(b.x, b.y); o.w = packbf2(b.z, b.w);
  ((uint4*)wb)[(size_t)row * 64 + lane] = o;
  float s = a.x * a.x + a.y * a.y + a.z * a.z + a.w * a.w
          + b.x * b.x + b.y * b.y + b.z * b.z + b.w * b.w;
#pragma unroll
  for (int m = 1; m < 64; m <<= 1) s += __shfl_xor(s, m);
  if (lane == 0) cnorm[row] = s;
}

// 256 thr = 4 waves (wr,wc in 2x2), tile 128 tokens x 128 codes, BK=64.
// Each wave owns a 64x64 sub-tile (4x4 frags of 16x16x32).
// Double-buffered 64KB LDS + 8KB cnorm; counted vmcnt(8); 2 raw barriers/step.
// grid: 1024 = 256 token-blocks x 4 code-splits (2048 codes = 16 ct tiles).
__global__ void __launch_bounds__(256) k_phase1(
    const unsigned short* __restrict__ zb, const unsigned short* __restrict__ wb,
    const float* __restrict__ cnorm, float* __restrict__ slotbuf) {
  __shared__ char Ab[2][16384];   // [sel][128 rows][64 k] bf16, xor-swizzled
  __shared__ char Bb[2][16384];
  __shared__ float cnLds[2048];   // this split's ||e||^2 panel

  const int tid  = threadIdx.x;
  const int lane = tid & 63;
  const int wv   = tid >> 6;
  const int wr   = wv >> 1;
  const int wc   = wv & 1;
  // bijective XCD swizzle: 2 XCDs per split -> 2MB B-panel L2-resident
  const int swz   = (blockIdx.x & 7) * 128 + (blockIdx.x >> 3);
  const int split = swz >> 8;   // 0..3
  const int tb    = swz & 255;  // 0..255
  const int l8   = lane >> 3;
  const int l15  = lane & 15;
  // staging source col-byte, pre-swizzled so linear global_load_lds dest holds
  // element (row, col ^ ((row&7)<<4)); row&7 == lane>>3 for every issue.
  const int cbsw = ((lane & 7) ^ l8) << 4;

  const char* srcA = (const char*)zb + (size_t)(tb * 128 + wv * 32 + l8) * 1024 + cbsw;
  const char* srcB = (const char*)wb + (size_t)(split * 2048 + wv * 32 + l8) * 1024 + cbsw;

  // frag read col-bytes: (ks*64 + (lane>>4)*16) ^ ((lane&7)<<4)
  const int csw0 = (((lane >> 4) << 4)) ^ ((lane & 7) << 4);
  const int csw1 = (64 + ((lane >> 4) << 4)) ^ ((lane & 7) << 4);
  int arow[4], brow[4];
#pragma unroll
  for (int i = 0; i < 4; ++i) {
    arow[i] = (wr * 64 + i * 16 + l15) << 7;
    brow[i] = (wc * 64 + i * 16 + l15) << 7;
  }

  const float BIG = 3.0e38f;
  float m1s[4][4], m2s[4][4];
#pragma unroll
  for (int mi = 0; mi < 4; ++mi)
#pragma unroll
    for (int r = 0; r < 4; ++r) { m1s[mi][r] = BIG; m2s[mi][r] = BIG; }

  const unsigned int KMASK = 0xFFFFE000u;

  // block prologue: cnorm panel -> LDS, stage step 0 into buf 0, full sync.
#pragma unroll
  for (int j = 0; j < 8; ++j) cnLds[tid + j * 256] = cnorm[split * 2048 + tid + j * 256];
#pragma unroll
  for (int r = 0; r < 4; ++r) gl_lds16(srcA + r * 8192, &Ab[0][wv * 4096 + r * 1024]);
#pragma unroll
  for (int r = 0; r < 4; ++r) gl_lds16(srcB + r * 8192, &Bb[0][wv * 4096 + r * 1024]);
  __syncthreads();  // drains prologue vmem + lds; queue is clean after this

  for (int ct = 0; ct < 16; ++ct) {
    const int codebase = split * 2048 + ct * 128 + wc * 64 + l15;
    const int cnb = ct * 128 + wc * 64 + l15;
    float cf0 = cnLds[cnb + 0];
    float cf1 = cnLds[cnb + 16];
    float cf2 = cnLds[cnb + 32];
    float cf3 = cnLds[cnb + 48];

    f32x4 acc[4][4];
#pragma unroll
    for (int mi = 0; mi < 4; ++mi) {
      f32x4 v0 = {cf0, cf0, cf0, cf0}; acc[mi][0] = v0;
      f32x4 v1 = {cf1, cf1, cf1, cf1}; acc[mi][1] = v1;
      f32x4 v2 = {cf2, cf2, cf2, cf2}; acc[mi][2] = v2;
      f32x4 v3 = {cf3, cf3, cf3, cf3}; acc[mi][3] = v3;
    }

    for (int kc = 0; kc < 8; ++kc) {
      const int s = ct * 8 + kc;
      const int sel = s & 1, tsel = sel ^ 1;
      if (s < 127) {
        const int s1 = s + 1;
        const int gA = (s1 & 7) * 128;
        const int gB = (s1 >> 3) * 131072 + (s1 & 7) * 128;
        char* dA = &Ab[tsel][wv * 4096];
        char* dB = &Bb[tsel][wv * 4096];
#pragma unroll
        for (int r = 0; r < 4; ++r) gl_lds16(srcA + gA + r * 8192, dA + r * 1024);
#pragma unroll
        for (int r = 0; r < 4; ++r) gl_lds16(srcB + gB + r * 8192, dB + r * 1024);
        asm volatile("s_waitcnt vmcnt(8)" ::: "memory");  // step s landed; s+1 in flight
      } else {
        asm volatile("s_waitcnt vmcnt(0)" ::: "memory");
      }
      SBAR;    // all waves' stage for step s complete -> buf[sel] ready
      SCHED0;  // pin ds_reads below the barrier

      const char* Ac = Ab[sel];
      const char* Bc = Bb[sel];
#pragma unroll
      for (int ks = 0; ks < 2; ++ks) {
        const int cs = ks ? csw1 : csw0;
        bf16x8 a[4], b[4];
#pragma unroll
        for (int i = 0; i < 4; ++i) {
          a[i] = *(const bf16x8*)(Ac + arow[i] + cs);
          b[i] = *(const bf16x8*)(Bc + brow[i] + cs);
        }
        __builtin_amdgcn_s_setprio(1);
#pragma unroll
        for (int fi = 0; fi < 4; ++fi)
#pragma unroll
          for (int fj = 0; fj < 4; ++fj)
            acc[fi][fj] = __builtin_amdgcn_mfma_f32_16x16x32_bf16(a[fi], b[fj], acc[fi][fj], 0, 0, 0);
        __builtin_amdgcn_s_setprio(0);
      }
      SBAR;  // reads of buf[sel] done -> next step may overwrite it
    }

    // epilogue: acc IS d = c - 2 z.e ; pack (d | code), fold into top-2
#pragma unroll
    for (int mi = 0; mi < 4; ++mi) {
#pragma unroll
      for (int r = 0; r < 4; ++r) {
        float k0 = __uint_as_float((__float_as_uint(acc[mi][0][r]) & KMASK) | (unsigned)(codebase + 0));
        float k1 = __uint_as_float((__float_as_uint(acc[mi][1][r]) & KMASK) | (unsigned)(codebase + 16));
        float k2 = __uint_as_float((__float_as_uint(acc[mi][2][r]) & KMASK) | (unsigned)(codebase + 32));
        float k3 = __uint_as_float((__float_as_uint(acc[mi][3][r]) & KMASK) | (unsigned)(codebase + 48));
        float lo01 = fminf(k0, k1), hi01 = fmaxf(k0, k1);
        float lo23 = fminf(k2, k3), hi23 = fmaxf(k2, k3);
        float a1 = fminf(lo01, lo23);
        float a2 = fminf(fmaxf(lo01, lo23), fminf(hi01, hi23));
        float M1 = m1s[mi][r], M2 = m2s[mi][r];
        m2s[mi][r] = fminf(fminf(M2, a2), fmaxf(M1, a1));
        m1s[mi][r] = fminf(M1, a1);
      }
    }
  }

  // cell = split*32 + wc*16 + col  (64 codes: all ct, nf for this (split,wc,col))
  const int cell = split * 32 + wc * 16 + l15;
#pragma unroll
  for (int mi = 0; mi < 4; ++mi) {
#pragma unroll
    for (int r = 0; r < 4; ++r) {
      int token = tb * 128 + wr * 64 + mi * 16 + (lane >> 4) * 4 + r;
      float2* p = (float2*)(slotbuf + (size_t)token * 256);
      p[cell] = make_float2(m1s[mi][r], m2s[mi][r]);
    }
  }
}

// one wave per token; exact f64 re-rank of margin candidates
__global__ void k_select(const float* __restrict__ slotbuf, const float* __restrict__ z,
                         const float* __restrict__ w, int* __restrict__ idxb,
                         unsigned int* __restrict__ counts) {
  const int lane = threadIdx.x & 63;
  const int t = blockIdx.x * 4 + (threadIdx.x >> 6);

  float4 e = *(const float4*)(slotbuf + (size_t)t * 256 + lane * 4);
  float p0 = e.x, p1 = e.y, p2 = e.z, p3 = e.w;  // cells 2*lane (m1,m2), 2*lane+1 (m1,m2)
  float pk = fminf(fminf(p0, p1), fminf(p2, p3));
#pragma unroll
  for (int m = 1; m < 64; m <<= 1) pk = fminf(pk, __shfl_xor(pk, m));
  const unsigned int mb = __float_as_uint(pk);
  int best = (int)(mb & 0x1FFFu);
  const float thr = __uint_as_float(mb & 0xFFFFE000u) + MARGIN;

  const unsigned int KM = 0xFFFFE000u;
  bool f0 = __uint_as_float(__float_as_uint(p0) & KM) < thr;
  bool f1 = __uint_as_float(__float_as_uint(p1) & KM) < thr;
  bool f2 = __uint_as_float(__float_as_uint(p2) & KM) < thr;
  bool f3 = __uint_as_float(__float_as_uint(p3) & KM) < thr;
  unsigned long long b0 = __ballot(f0), b1 = __ballot(f1);
  unsigned long long b2 = __ballot(f2), b3 = __ballot(f3);
  int nc = __popcll(b0) + __popcll(b1) + __popcll(b2) + __popcll(b3);

  if (nc > 1) {
    const float4* zp = (const float4*)(z + (size_t)t * DIM) + lane * 2;
    float4 za = zp[0], zc = zp[1];
    double bestd = 1e300;
    int besti = NE;

    auto eval = [&](int code) {
      const float4* wp = (const float4*)(w + (size_t)code * DIM) + lane * 2;
      float4 wa = wp[0], wv2 = wp[1];
      double d = (double)wa.x * ((double)wa.x - 2.0 * (double)za.x)
               + (double)wa.y * ((double)wa.y - 2.0 * (double)za.y)
               + (double)wa.z * ((double)wa.z - 2.0 * (double)za.z)
               + (double)wa.w * ((double)wa.w - 2.0 * (double)za.w)
               + (double)wv2.x * ((double)wv2.x - 2.0 * (double)zc.x)
               + (double)wv2.y * ((double)wv2.y - 2.0 * (double)zc.y)
               + (double)wv2.z * ((double)wv2.z - 2.0 * (double)zc.z)
               + (double)wv2.w * ((double)wv2.w - 2.0 * (double)zc.w);
#pragma unroll
      for (int m = 1; m < 64; m <<= 1) d += __shfl_xor(d, m);
      if (d < bestd || (d == bestd && code < besti)) { bestd = d; besti = code; }
    };
    // cell = (split, wc, col): codes sp*2048 + ct*128 + wcc*64 + nf*16 + col
    auto scan_cell = [&](int cid) {
      int sp = cid >> 5, wcc = (cid >> 4) & 1, col = cid & 15;
      int base = sp * 2048 + wcc * 64 + col;
      for (int ctt = 0; ctt < 16; ++ctt)
        for (int nf = 0; nf < 4; ++nf)
          eval(base + ctt * 128 + nf * 16);
    };

    int i0 = (int)(__float_as_uint(p0) & 0x1FFFu);
    int i1 = (int)(__float_as_uint(p1) & 0x1FFFu);
    int i2 = (int)(__float_as_uint(p2) & 0x1FFFu);
    int i3 = (int)(__float_as_uint(p3) & 0x1FFFu);
    unsigned long long bm;
    bm = b0; while (bm) { int s = __ffsll(bm) - 1; bm &= bm - 1; eval(__shfl(i0, s)); }
    bm = b1; while (bm) { int s = __ffsll(bm) - 1; bm &= bm - 1; eval(__shfl(i1, s)); }
    bm = b2; while (bm) { int s = __ffsll(bm) - 1; bm &= bm - 1; eval(__shfl(i2, s)); }
    bm = b3; while (bm) { int s = __ffsll(bm) - 1; bm &= bm - 1; eval(__shfl(i3, s)); }
    unsigned long long h0 = __ballot(f0 && f1);
    unsigned long long h1 = __ballot(f2 && f3);
    bm = h0; while (bm) { int s = __ffsll(bm) - 1; bm &= bm - 1; scan_cell(2 * s); }
    bm = h1; while (bm) { int s = __ffsll(bm) - 1; bm &= bm - 1; scan_cell(2 * s + 1); }
    best = besti;
  }
  if (lane == 0) {
    idxb[t] = best;
    atomicAdd(&counts[best], 1u);
  }
}

__global__ void k_gather(const float* __restrict__ w, const int* __restrict__ idxb,
                         float* __restrict__ out) {
  int n = blockIdx.x * 2 + (threadIdx.x >> 7);
  int j = threadIdx.x & 127;
  int k = idxb[n];
  ((float4*)out)[(size_t)n * 128 + j] = ((const float4*)w)[(size_t)k * 128 + j];
}

__global__ void k_perp(const unsigned int* __restrict__ counts, float* __restrict__ out) {
  __shared__ float red[16];
  float s = 0.f;
  for (int k = threadIdx.x; k < NE; k += 1024) {
    float p = (float)counts[k] * (1.0f / (float)NTOK);
    s += p * logf(p + 1e-10f);
  }
#pragma unroll
  for (int m = 1; m < 64; m <<= 1) s += __shfl_xor(s, m);
  int lane = threadIdx.x & 63, wv = threadIdx.x >> 6;
  if (lane == 0) red[wv] = s;
  __syncthreads();
  if (threadIdx.x == 0) {
    float tot = 0.f;
    for (int i = 0; i < 16; ++i) tot += red[i];
    out[(size_t)NTOK * DIM] = expf(-tot);
  }
}

extern "C" void kernel_launch(void* const* d_in, const int* in_sizes, int n_in,
                              void* d_out, int out_size, void* d_ws, size_t ws_size,
                              hipStream_t stream) {
  const float* z = (const float*)d_in[0];
  const float* w = (const float*)d_in[1];
  float* out = (float*)d_out;
  char* ws = (char*)d_ws;

  unsigned int* zb      = (unsigned int*)(ws);
  unsigned int* wb      = (unsigned int*)(ws + 33554432);
  float*        cnorm   = (float*)(ws + 41943040);
  float*        slotbuf = (float*)(ws + 41975808);
  int*          idxb    = (int*)(ws + 75530240);
  unsigned int* counts  = (unsigned int*)(ws + 75661312);

  k_prep_z<<<8192, 256, 0, stream>>>(z, zb);
  k_prep_w<<<2048, 256, 0, stream>>>(w, wb, cnorm);
  k_phase1<<<1024, 256, 0, stream>>>((const unsigned short*)zb, (const unsigned short*)wb,
                                     cnorm, slotbuf);
  hipMemsetAsync(counts, 0, NE * sizeof(unsigned int), stream);
  k_select<<<8192, 256, 0, stream>>>(slotbuf, z, w, idxb, counts);
  k_gather<<<16384, 256, 0, stream>>>(w, idxb, out);
  k_perp<<<1, 1024, 0, stream>>>(counts, out);
}

// Round 6
// 458.927 us; speedup vs baseline: 1.2969x; 1.2969x over previous
//
#include <hip/hip_runtime.h>
#include <stdint.h>

// VectorQuantizer: z[32768,512] f32, weight[8192,512] f32 ->
//   out[0 .. 32768*512) = z_q = weight[argmin_k ||z-e_k||^2]  (exact fp32 rows)
//   out[32768*512]      = perplexity
//
// Pipeline:
//  1) k_prep_z: bf16(-2z); k_prep_w: bf16(w) + exact f32 row norms c_k
//  2) k_phase1: 256x256 tile, 8 waves (4M x 2N, wave 64x128), BK=32,
//     QUAD-buffered LDS (4 x 32KB), counted vmcnt(12) = 3-tile prefetch
//     distance (T3+T4), setprio around MFMA clusters (T5), XOR-swizzled
//     64B LDS rows (T2). acc init = ||e||^2, MFMA accumulates (-2z).e ->
//     d = c - 2 z.e directly. Per token: top-2 packed keys
//     (quantized d | 13-bit code) per 128 cells (= split,wcN,col; 64 codes).
//  3) k_select: global min; margin candidates re-ranked with exact f64 dots
//     (cells with both entries in margin fully rescanned); idx + histogram
//  4) k_gather: z_q rows ; k_perp: perplexity
//
// ws layout (bytes): zb@0 32MB | wb@33554432 8MB | cnorm@41943040 32KB |
//   slot@41975808 32MB | idx@75530240 128KB | counts@75661312 32KB

#define NTOK 32768
#define NE   8192
#define DIM  512
#define MARGIN 4.0f

typedef __attribute__((ext_vector_type(8))) short bf16x8;
typedef __attribute__((ext_vector_type(4))) float f32x4;

#define SBAR   __builtin_amdgcn_s_barrier()
#define SCHED0 __builtin_amdgcn_sched_barrier(0)

__device__ __forceinline__ unsigned int f2bf1(float x) {
  unsigned int u = __float_as_uint(x);
  return (u + 0x7FFFu + ((u >> 16) & 1u)) >> 16;
}
__device__ __forceinline__ unsigned int packbf2(float lo, float hi) {
  return f2bf1(lo) | (f2bf1(hi) << 16);
}

__device__ __forceinline__ void gl_lds16(const void* g, void* l) {
  __builtin_amdgcn_global_load_lds(
      (const __attribute__((address_space(1))) void*)g,
      (__attribute__((address_space(3))) void*)l, 16, 0, 0);
}

__global__ void k_prep_z(const float* __restrict__ z, unsigned int* __restrict__ zb) {
  int i = blockIdx.x * 256 + threadIdx.x;  // one thread per 8 floats
  const float4* zp = (const float4*)z + (size_t)i * 2;
  float4 a = zp[0], b = zp[1];
  uint4 o;  // store bf16(-2z): exact 2x scaling, same rounding as bf16(z)
  o.x = packbf2(-2.f * a.x, -2.f * a.y); o.y = packbf2(-2.f * a.z, -2.f * a.w);
  o.z = packbf2(-2.f * b.x, -2.f * b.y); o.w = packbf2(-2.f * b.z, -2.f * b.w);
  ((uint4*)zb)[i] = o;
}

__global__ void k_prep_w(const float* __restrict__ w, unsigned int* __restrict__ wb,
                         float* __restrict__ cnorm) {
  int row  = blockIdx.x * 4 + (threadIdx.x >> 6);  // one wave per code row
  int lane = threadIdx.x & 63;
  const float4* wp = (const float4*)(w + (size_t)row * DIM) + lane * 2;
  float4 a = wp[0], b = wp[1];
  uint4 o;
  o.x = packbf2(a.x, a.y); o.y = packbf2(a.z, a.w);
  o.z = packbf2(b.x, b.y); o.w = packbf2(b.z, b.w);
  ((uint4*)wb)[(size_t)row * 64 + lane] = o;
  float s = a.x * a.x + a.y * a.y + a.z * a.z + a.w * a.w
          + b.x * b.x + b.y * b.y + b.z * b.z + b.w * b.w;
#pragma unroll
  for (int m = 1; m < 64; m <<= 1) s += __shfl_xor(s, m);
  if (lane == 0) cnorm[row] = s;
}

// 512 thr = 8 waves (wrM 0..3 token quarter, wcN 0..1 code half).
// Tile 256 tok x 256 codes, BK=32; wave tile 64x128 = 4mi x 8fj frags.
// LDS: 4 slots x (A 16KB | B 16KB); per tile: 4 gl_lds/wave; vmcnt(12).
// grid 512 = 128 tb x 4 splits (2048 codes = 8 ct x 256), XCD-chunked.
__global__ void __launch_bounds__(512, 2) k_phase1(
    const unsigned short* __restrict__ zb, const unsigned short* __restrict__ wb,
    const float* __restrict__ cnorm, float* __restrict__ slotbuf) {
  __shared__ char S[4][32768];    // [slot][A: 256 rows x 64B | B: 256 rows x 64B]
  __shared__ float cnLds[2048];   // this split's ||e||^2 panel

  const int tid  = threadIdx.x;
  const int lane = tid & 63;
  const int wv   = tid >> 6;
  const int wrM  = wv >> 1;
  const int wcN  = wv & 1;
  const int swzb  = (blockIdx.x & 7) * 64 + (blockIdx.x >> 3);
  const int split = swzb >> 7;   // 0..3
  const int tb    = swzb & 127;  // 0..127
  const int l15  = lane & 15;

  // 64B-row XOR swizzle: element (row,c16slot) stored at slot c ^ ((row>>1)&3).
  // Staging (linear gl_lds dest): lane l -> row +=(l>>2), slot l&3 ->
  // source col-slot = (l&3) ^ ((l>>3)&3)   [(row>>1)&3 == (l>>3)&3, bases =0 mod4]
  const int srcsw = (((lane & 3) ^ ((lane >> 3) & 3)) << 4);
  const char* zsA = (const char*)zb + (size_t)(tb * 256 + wv * 32 + (lane >> 2)) * 1024 + srcsw;
  const char* zsB = (const char*)wb + (size_t)(split * 2048 + wv * 32 + (lane >> 2)) * 1024 + srcsw;

  // Frag read: k-group g=lane>>4, row ...+l15 -> byte row*64 + ((g^((row>>1)&3))<<4);
  // (row>>1)&3 == (lane>>1)&3 for every frag row (all bases = 0 mod 4).
  const int rdsw = ((((lane >> 4) ^ (lane >> 1)) & 3) << 4);
  int arow[4], brow[8];
#pragma unroll
  for (int mi = 0; mi < 4; ++mi) arow[mi] = (wrM * 64 + mi * 16 + l15) * 64 + rdsw;
#pragma unroll
  for (int fj = 0; fj < 8; ++fj) brow[fj] = 16384 + (wcN * 128 + fj * 16 + l15) * 64 + rdsw;

  const float BIG = 3.0e38f;
  float m1s[4][4], m2s[4][4];
#pragma unroll
  for (int mi = 0; mi < 4; ++mi)
#pragma unroll
    for (int r = 0; r < 4; ++r) { m1s[mi][r] = BIG; m2s[mi][r] = BIG; }

  const unsigned int KMASK = 0xFFFFE000u;

  // stage tile t into slot t&3 (4 loads/wave: A rows wv*32..+31, B same rows)
  auto stage = [&](int t) {
    char* Sb = &S[t & 3][wv * 2048];
    const char* ga = zsA + ((t & 15) << 6);
    gl_lds16(ga, Sb);
    gl_lds16(ga + 16 * 1024, Sb + 1024);
    const char* gb = zsB + ((t >> 4) << 18) + ((t & 15) << 6);
    gl_lds16(gb, Sb + 16384);
    gl_lds16(gb + 16 * 1024, Sb + 16384 + 1024);
  };

  // prologue: cnorm panel -> LDS; stage tiles 0..2; full drain once.
#pragma unroll
  for (int j = 0; j < 4; ++j) cnLds[tid + j * 512] = cnorm[split * 2048 + tid + j * 512];
  stage(0); stage(1); stage(2);
  __syncthreads();

  for (int ct = 0; ct < 8; ++ct) {
    const int codebase = split * 2048 + ct * 256 + wcN * 128 + l15;
    float cf[8];
#pragma unroll
    for (int fj = 0; fj < 8; ++fj) cf[fj] = cnLds[ct * 256 + wcN * 128 + fj * 16 + l15];
    f32x4 acc[4][8];
#pragma unroll
    for (int mi = 0; mi < 4; ++mi)
#pragma unroll
      for (int fj = 0; fj < 8; ++fj) {
        f32x4 v = {cf[fj], cf[fj], cf[fj], cf[fj]};
        acc[mi][fj] = v;  // d = c + (-2z).e accumulated by MFMA
      }

    for (int kc = 0; kc < 16; ++kc) {
      const int s = ct * 16 + kc;
      // counted-vmcnt pipeline: issue s+3, wait for s (12 = 3 tiles x 4 loads)
      if (s <= 124) { stage(s + 3); asm volatile("s_waitcnt vmcnt(12)" ::: "memory"); }
      else if (s == 125) { asm volatile("s_waitcnt vmcnt(8)" ::: "memory"); }
      else if (s == 126) { asm volatile("s_waitcnt vmcnt(4)" ::: "memory"); }
      else               { asm volatile("s_waitcnt vmcnt(0)" ::: "memory"); }
      SBAR;    // all waves' stage of tile s landed -> slot s&3 ready
      SCHED0;  // pin the ds_reads below the barrier

      const char* P = S[s & 3];
      bf16x8 a[4];
#pragma unroll
      for (int mi = 0; mi < 4; ++mi) a[mi] = *(const bf16x8*)(P + arow[mi]);
      {
        bf16x8 b0[4];
#pragma unroll
        for (int fj = 0; fj < 4; ++fj) b0[fj] = *(const bf16x8*)(P + brow[fj]);
        __builtin_amdgcn_s_setprio(1);
#pragma unroll
        for (int mi = 0; mi < 4; ++mi)
#pragma unroll
          for (int fj = 0; fj < 4; ++fj)
            acc[mi][fj] = __builtin_amdgcn_mfma_f32_16x16x32_bf16(a[mi], b0[fj], acc[mi][fj], 0, 0, 0);
        __builtin_amdgcn_s_setprio(0);
      }
      {
        bf16x8 b1[4];
#pragma unroll
        for (int fj = 0; fj < 4; ++fj) b1[fj] = *(const bf16x8*)(P + brow[fj + 4]);
        __builtin_amdgcn_s_setprio(1);
#pragma unroll
        for (int mi = 0; mi < 4; ++mi)
#pragma unroll
          for (int fj = 0; fj < 4; ++fj)
            acc[mi][fj + 4] = __builtin_amdgcn_mfma_f32_16x16x32_bf16(a[mi], b1[fj], acc[mi][fj + 4], 0, 0, 0);
        __builtin_amdgcn_s_setprio(0);
      }
      SBAR;  // reads of slot s&3 done -> tile s+4 may overwrite it
    }

    // epilogue: acc IS d = c - 2 z.e ; pack (quantized d | code), top-2 insert
#pragma unroll
    for (int mi = 0; mi < 4; ++mi) {
#pragma unroll
      for (int r = 0; r < 4; ++r) {
        float M1 = m1s[mi][r], M2 = m2s[mi][r];
#pragma unroll
        for (int fj = 0; fj < 8; ++fj) {
          float kf = __uint_as_float((__float_as_uint(acc[mi][fj][r]) & KMASK) |
                                     (unsigned)(codebase + fj * 16));
          M2 = fminf(M2, fmaxf(M1, kf));
          M1 = fminf(M1, kf);
        }
        m1s[mi][r] = M1; m2s[mi][r] = M2;
      }
    }
  }

  // cell = split*32 + wcN*16 + col  (64 codes: ct 8 x fj 8)
  const int cell = split * 32 + wcN * 16 + l15;
#pragma unroll
  for (int mi = 0; mi < 4; ++mi) {
#pragma unroll
    for (int r = 0; r < 4; ++r) {
      int token = tb * 256 + wrM * 64 + mi * 16 + (lane >> 4) * 4 + r;
      float2* p = (float2*)(slotbuf + (size_t)token * 256);
      p[cell] = make_float2(m1s[mi][r], m2s[mi][r]);
    }
  }
}

// one wave per token; exact f64 re-rank of margin candidates
__global__ void k_select(const float* __restrict__ slotbuf, const float* __restrict__ z,
                         const float* __restrict__ w, int* __restrict__ idxb,
                         unsigned int* __restrict__ counts) {
  const int lane = threadIdx.x & 63;
  const int t = blockIdx.x * 4 + (threadIdx.x >> 6);

  float4 e = *(const float4*)(slotbuf + (size_t)t * 256 + lane * 4);
  float p0 = e.x, p1 = e.y, p2 = e.z, p3 = e.w;  // cells 2*lane (m1,m2), 2*lane+1 (m1,m2)
  float pk = fminf(fminf(p0, p1), fminf(p2, p3));
#pragma unroll
  for (int m = 1; m < 64; m <<= 1) pk = fminf(pk, __shfl_xor(pk, m));
  const unsigned int mb = __float_as_uint(pk);
  int best = (int)(mb & 0x1FFFu);
  const float thr = __uint_as_float(mb & 0xFFFFE000u) + MARGIN;

  const unsigned int KM = 0xFFFFE000u;
  bool f0 = __uint_as_float(__float_as_uint(p0) & KM) < thr;
  bool f1 = __uint_as_float(__float_as_uint(p1) & KM) < thr;
  bool f2 = __uint_as_float(__float_as_uint(p2) & KM) < thr;
  bool f3 = __uint_as_float(__float_as_uint(p3) & KM) < thr;
  unsigned long long b0 = __ballot(f0), b1 = __ballot(f1);
  unsigned long long b2 = __ballot(f2), b3 = __ballot(f3);
  int nc = __popcll(b0) + __popcll(b1) + __popcll(b2) + __popcll(b3);

  if (nc > 1) {
    const float4* zp = (const float4*)(z + (size_t)t * DIM) + lane * 2;
    float4 za = zp[0], zc = zp[1];
    double bestd = 1e300;
    int besti = NE;

    auto eval = [&](int code) {
      const float4* wp = (const float4*)(w + (size_t)code * DIM) + lane * 2;
      float4 wa = wp[0], wv2 = wp[1];
      double d = (double)wa.x * ((double)wa.x - 2.0 * (double)za.x)
               + (double)wa.y * ((double)wa.y - 2.0 * (double)za.y)
               + (double)wa.z * ((double)wa.z - 2.0 * (double)za.z)
               + (double)wa.w * ((double)wa.w - 2.0 * (double)za.w)
               + (double)wv2.x * ((double)wv2.x - 2.0 * (double)zc.x)
               + (double)wv2.y * ((double)wv2.y - 2.0 * (double)zc.y)
               + (double)wv2.z * ((double)wv2.z - 2.0 * (double)zc.z)
               + (double)wv2.w * ((double)wv2.w - 2.0 * (double)zc.w);
#pragma unroll
      for (int m = 1; m < 64; m <<= 1) d += __shfl_xor(d, m);
      if (d < bestd || (d == bestd && code < besti)) { bestd = d; besti = code; }
    };
    // cell = (split, wcN, col): codes sp*2048 + ct*256 + wcN*128 + fj*16 + col
    auto scan_cell = [&](int cid) {
      int sp = cid >> 5, wcc = (cid >> 4) & 1, col = cid & 15;
      int base = sp * 2048 + wcc * 128 + col;
      for (int ctt = 0; ctt < 8; ++ctt)
        for (int fj = 0; fj < 8; ++fj)
          eval(base + ctt * 256 + fj * 16);
    };

    int i0 = (int)(__float_as_uint(p0) & 0x1FFFu);
    int i1 = (int)(__float_as_uint(p1) & 0x1FFFu);
    int i2 = (int)(__float_as_uint(p2) & 0x1FFFu);
    int i3 = (int)(__float_as_uint(p3) & 0x1FFFu);
    unsigned long long bm;
    bm = b0; while (bm) { int s = __ffsll(bm) - 1; bm &= bm - 1; eval(__shfl(i0, s)); }
    bm = b1; while (bm) { int s = __ffsll(bm) - 1; bm &= bm - 1; eval(__shfl(i1, s)); }
    bm = b2; while (bm) { int s = __ffsll(bm) - 1; bm &= bm - 1; eval(__shfl(i2, s)); }
    bm = b3; while (bm) { int s = __ffsll(bm) - 1; bm &= bm - 1; eval(__shfl(i3, s)); }
    unsigned long long h0 = __ballot(f0 && f1);
    unsigned long long h1 = __ballot(f2 && f3);
    bm = h0; while (bm) { int s = __ffsll(bm) - 1; bm &= bm - 1; scan_cell(2 * s); }
    bm = h1; while (bm) { int s = __ffsll(bm) - 1; bm &= bm - 1; scan_cell(2 * s + 1); }
    best = besti;
  }
  if (lane == 0) {
    idxb[t] = best;
    atomicAdd(&counts[best], 1u);
  }
}

__global__ void k_gather(const float* __restrict__ w, const int* __restrict__ idxb,
                         float* __restrict__ out) {
  int n = blockIdx.x * 2 + (threadIdx.x >> 7);
  int j = threadIdx.x & 127;
  int k = idxb[n];
  ((float4*)out)[(size_t)n * 128 + j] = ((const float4*)w)[(size_t)k * 128 + j];
}

__global__ void k_perp(const unsigned int* __restrict__ counts, float* __restrict__ out) {
  __shared__ float red[16];
  float s = 0.f;
  for (int k = threadIdx.x; k < NE; k += 1024) {
    float p = (float)counts[k] * (1.0f / (float)NTOK);
    s += p * logf(p + 1e-10f);
  }
#pragma unroll
  for (int m = 1; m < 64; m <<= 1) s += __shfl_xor(s, m);
  int lane = threadIdx.x & 63, wv = threadIdx.x >> 6;
  if (lane == 0) red[wv] = s;
  __syncthreads();
  if (threadIdx.x == 0) {
    float tot = 0.f;
    for (int i = 0; i < 16; ++i) tot += red[i];
    out[(size_t)NTOK * DIM] = expf(-tot);
  }
}

extern "C" void kernel_launch(void* const* d_in, const int* in_sizes, int n_in,
                              void* d_out, int out_size, void* d_ws, size_t ws_size,
                              hipStream_t stream) {
  const float* z = (const float*)d_in[0];
  const float* w = (const float*)d_in[1];
  float* out = (float*)d_out;
  char* ws = (char*)d_ws;

  unsigned int* zb      = (unsigned int*)(ws);
  unsigned int* wb      = (unsigned int*)(ws + 33554432);
  float*        cnorm   = (float*)(ws + 41943040);
  float*        slotbuf = (float*)(ws + 41975808);
  int*          idxb    = (int*)(ws + 75530240);
  unsigned int* counts  = (unsigned int*)(ws + 75661312);

  k_prep_z<<<8192, 256, 0, stream>>>(z, zb);
  k_prep_w<<<2048, 256, 0, stream>>>(w, wb, cnorm);
  k_phase1<<<512, 512, 0, stream>>>((const unsigned short*)zb, (const unsigned short*)wb,
                                    cnorm, slotbuf);
  hipMemsetAsync(counts, 0, NE * sizeof(unsigned int), stream);
  k_select<<<8192, 256, 0, stream>>>(slotbuf, z, w, idxb, counts);
  k_gather<<<16384, 256, 0, stream>>>(w, idxb, out);
  k_perp<<<1, 1024, 0, stream>>>(counts, out);
}

// Round 7
// 454.679 us; speedup vs baseline: 1.3090x; 1.0093x over previous
//
#include <hip/hip_runtime.h>
#include <stdint.h>

// VectorQuantizer: z[32768,512] f32, weight[8192,512] f32 ->
//   out[0 .. 32768*512) = z_q = weight[argmin_k ||z-e_k||^2]  (exact fp32 rows)
//   out[32768*512]      = perplexity
//
// Pipeline:
//  1) k_prep_z: bf16(-2z); k_prep_w: bf16(w) + exact f32 row norms c_k
//  2) k_phase1: 256x256 tile, 8 waves (4M x 2N, wave 64x128), BK=32,
//     QUAD-buffered LDS (4 x 32KB), counted vmcnt (3-tile prefetch, T4),
//     2 paced phases per tile {ds_read || stage-half -> SBAR -> lgkm0 ->
//     setprio MFMA x16 -> SBAR} (T3 fine interleave + T5), XOR-swizzled
//     64B LDS rows (T2). acc init = ||e||^2, MFMA accumulates (-2z).e ->
//     d = c - 2 z.e directly. Per token: top-2 packed keys
//     (quantized d | 13-bit code) per 128 cells (= split,wcN,col; 64 codes).
//  3) k_select: global min; margin candidates re-ranked with exact f64 dots
//     (cells with both entries in margin fully rescanned); idx + histogram
//  4) k_gather: z_q rows ; k_perp: perplexity
//
// ws layout (bytes): zb@0 32MB | wb@33554432 8MB | cnorm@41943040 32KB |
//   slot@41975808 32MB | idx@75530240 128KB | counts@75661312 32KB

#define NTOK 32768
#define NE   8192
#define DIM  512
#define MARGIN 4.0f

typedef __attribute__((ext_vector_type(8))) short bf16x8;
typedef __attribute__((ext_vector_type(4))) float f32x4;

#define SBAR   __builtin_amdgcn_s_barrier()
#define SCHED0 __builtin_amdgcn_sched_barrier(0)
#define LGKM0  asm volatile("s_waitcnt lgkmcnt(0)" ::: "memory")

__device__ __forceinline__ unsigned int f2bf1(float x) {
  unsigned int u = __float_as_uint(x);
  return (u + 0x7FFFu + ((u >> 16) & 1u)) >> 16;
}
__device__ __forceinline__ unsigned int packbf2(float lo, float hi) {
  return f2bf1(lo) | (f2bf1(hi) << 16);
}

__device__ __forceinline__ void gl_lds16(const void* g, void* l) {
  __builtin_amdgcn_global_load_lds(
      (const __attribute__((address_space(1))) void*)g,
      (__attribute__((address_space(3))) void*)l, 16, 0, 0);
}

__global__ void k_prep_z(const float* __restrict__ z, unsigned int* __restrict__ zb) {
  int i = blockIdx.x * 256 + threadIdx.x;  // one thread per 8 floats
  const float4* zp = (const float4*)z + (size_t)i * 2;
  float4 a = zp[0], b = zp[1];
  uint4 o;  // store bf16(-2z): exact 2x scaling, same rounding as bf16(z)
  o.x = packbf2(-2.f * a.x, -2.f * a.y); o.y = packbf2(-2.f * a.z, -2.f * a.w);
  o.z = packbf2(-2.f * b.x, -2.f * b.y); o.w = packbf2(-2.f * b.z, -2.f * b.w);
  ((uint4*)zb)[i] = o;
}

__global__ void k_prep_w(const float* __restrict__ w, unsigned int* __restrict__ wb,
                         float* __restrict__ cnorm) {
  int row  = blockIdx.x * 4 + (threadIdx.x >> 6);  // one wave per code row
  int lane = threadIdx.x & 63;
  const float4* wp = (const float4*)(w + (size_t)row * DIM) + lane * 2;
  float4 a = wp[0], b = wp[1];
  uint4 o;
  o.x = packbf2(a.x, a.y); o.y = packbf2(a.z, a.w);
  o.z = packbf2(b.x, b.y); o.w = packbf2(b.z, b.w);
  ((uint4*)wb)[(size_t)row * 64 + lane] = o;
  float s = a.x * a.x + a.y * a.y + a.z * a.z + a.w * a.w
          + b.x * b.x + b.y * b.y + b.z * b.z + b.w * b.w;
#pragma unroll
  for (int m = 1; m < 64; m <<= 1) s += __shfl_xor(s, m);
  if (lane == 0) cnorm[row] = s;
}

// 512 thr = 8 waves (wrM 0..3 token quarter, wcN 0..1 code half).
// Tile 256 tok x 256 codes, BK=32; wave tile 64x128 = 4mi x 8fj frags.
// LDS: 4 slots x (A 16KB | B 16KB); stage split 2+2; vmcnt(10)/(8)/(4)/(0).
// grid 512 = 128 tb x 4 splits (2048 codes = 8 ct x 256), XCD-chunked.
__global__ void __launch_bounds__(512, 2) k_phase1(
    const unsigned short* __restrict__ zb, const unsigned short* __restrict__ wb,
    const float* __restrict__ cnorm, float* __restrict__ slotbuf) {
  __shared__ char S[4][32768];    // [slot][A: 256 rows x 64B | B: 256 rows x 64B]
  __shared__ float cnLds[2048];   // this split's ||e||^2 panel

  const int tid  = threadIdx.x;
  const int lane = tid & 63;
  const int wv   = tid >> 6;
  const int wrM  = wv >> 1;
  const int wcN  = wv & 1;
  const int swzb  = (blockIdx.x & 7) * 64 + (blockIdx.x >> 3);
  const int split = swzb >> 7;   // 0..3
  const int tb    = swzb & 127;  // 0..127
  const int l15  = lane & 15;

  // 64B-row XOR swizzle: element (row,c16slot) stored at slot c ^ ((row>>1)&3).
  // Staging (linear gl_lds dest): lane l -> row +=(l>>2), slot l&3 ->
  // source col-slot = (l&3) ^ ((l>>3)&3)   [(row>>1)&3 == (l>>3)&3, bases =0 mod4]
  const int srcsw = (((lane & 3) ^ ((lane >> 3) & 3)) << 4);
  const char* zsA = (const char*)zb + (size_t)(tb * 256 + wv * 32 + (lane >> 2)) * 1024 + srcsw;
  const char* zsB = (const char*)wb + (size_t)(split * 2048 + wv * 32 + (lane >> 2)) * 1024 + srcsw;

  // Frag read: k-group g=lane>>4, row ...+l15 -> byte row*64 + ((g^((row>>1)&3))<<4);
  // (row>>1)&3 == (lane>>1)&3 for every frag row (all bases = 0 mod 4).
  const int rdsw = ((((lane >> 4) ^ (lane >> 1)) & 3) << 4);
  int arow[4], brow[8];
#pragma unroll
  for (int mi = 0; mi < 4; ++mi) arow[mi] = (wrM * 64 + mi * 16 + l15) * 64 + rdsw;
#pragma unroll
  for (int fj = 0; fj < 8; ++fj) brow[fj] = 16384 + (wcN * 128 + fj * 16 + l15) * 64 + rdsw;

  const float BIG = 3.0e38f;
  float m1s[4][4], m2s[4][4];
#pragma unroll
  for (int mi = 0; mi < 4; ++mi)
#pragma unroll
    for (int r = 0; r < 4; ++r) { m1s[mi][r] = BIG; m2s[mi][r] = BIG; }

  const unsigned int KMASK = 0xFFFFE000u;

  // stage halves of tile t into slot t&3 (2 loads each per wave)
  auto stageA = [&](int t) {
    char* Sb = &S[t & 3][wv * 2048];
    const char* ga = zsA + ((t & 15) << 6);
    gl_lds16(ga, Sb);
    gl_lds16(ga + 16 * 1024, Sb + 1024);
  };
  auto stageB = [&](int t) {
    char* Sb = &S[t & 3][wv * 2048];
    const char* gb = zsB + ((t >> 4) << 18) + ((t & 15) << 6);
    gl_lds16(gb, Sb + 16384);
    gl_lds16(gb + 16 * 1024, Sb + 16384 + 1024);
  };

  // prologue: cnorm panel -> LDS; stage tiles 0..2; full drain once.
#pragma unroll
  for (int j = 0; j < 4; ++j) cnLds[tid + j * 512] = cnorm[split * 2048 + tid + j * 512];
  stageA(0); stageB(0); stageA(1); stageB(1); stageA(2); stageB(2);
  __syncthreads();

  for (int ct = 0; ct < 8; ++ct) {
    const int codebase = split * 2048 + ct * 256 + wcN * 128 + l15;
    float cf[8];
#pragma unroll
    for (int fj = 0; fj < 8; ++fj) cf[fj] = cnLds[ct * 256 + wcN * 128 + fj * 16 + l15];
    f32x4 acc[4][8];
#pragma unroll
    for (int mi = 0; mi < 4; ++mi)
#pragma unroll
      for (int fj = 0; fj < 8; ++fj) {
        f32x4 v = {cf[fj], cf[fj], cf[fj], cf[fj]};
        acc[mi][fj] = v;  // d = c + (-2z).e accumulated by MFMA
      }

    for (int kc = 0; kc < 16; ++kc) {
      const int s = ct * 16 + kc;
      // tile entry: issue A(s+3), counted wait for tile s (10 newer loads in flight)
      if (s <= 124) { stageA(s + 3); asm volatile("s_waitcnt vmcnt(10)" ::: "memory"); }
      else if (s == 125) { asm volatile("s_waitcnt vmcnt(8)" ::: "memory"); }
      else if (s == 126) { asm volatile("s_waitcnt vmcnt(4)" ::: "memory"); }
      else               { asm volatile("s_waitcnt vmcnt(0)" ::: "memory"); }
      SBAR;    // slot s&3 ready across all waves

      const char* P = S[s & 3];
      // ---- phase 0: read a[0..3], b[0..3]; pace; 16 MFMA
      bf16x8 a[4], b0[4];
#pragma unroll
      for (int mi = 0; mi < 4; ++mi) a[mi] = *(const bf16x8*)(P + arow[mi]);
#pragma unroll
      for (int fj = 0; fj < 4; ++fj) b0[fj] = *(const bf16x8*)(P + brow[fj]);
      SBAR;
      LGKM0; SCHED0;
      __builtin_amdgcn_s_setprio(1);
#pragma unroll
      for (int mi = 0; mi < 4; ++mi)
#pragma unroll
        for (int fj = 0; fj < 4; ++fj)
          acc[mi][fj] = __builtin_amdgcn_mfma_f32_16x16x32_bf16(a[mi], b0[fj], acc[mi][fj], 0, 0, 0);
      __builtin_amdgcn_s_setprio(0);
      SBAR;

      // ---- phase 1: read b[4..7]; issue B(s+3); pace; 16 MFMA
      bf16x8 b1[4];
#pragma unroll
      for (int fj = 0; fj < 4; ++fj) b1[fj] = *(const bf16x8*)(P + brow[fj + 4]);
      if (s <= 124) stageB(s + 3);
      SBAR;
      LGKM0; SCHED0;
      __builtin_amdgcn_s_setprio(1);
#pragma unroll
      for (int mi = 0; mi < 4; ++mi)
#pragma unroll
        for (int fj = 0; fj < 4; ++fj)
          acc[mi][fj + 4] = __builtin_amdgcn_mfma_f32_16x16x32_bf16(a[mi], b1[fj], acc[mi][fj + 4], 0, 0, 0);
      __builtin_amdgcn_s_setprio(0);
      SBAR;  // reads of slot s&3 done -> tile s+4 may overwrite it
    }

    // epilogue: acc IS d = c - 2 z.e ; pack (quantized d | code), top-2 insert
#pragma unroll
    for (int mi = 0; mi < 4; ++mi) {
#pragma unroll
      for (int r = 0; r < 4; ++r) {
        float M1 = m1s[mi][r], M2 = m2s[mi][r];
#pragma unroll
        for (int fj = 0; fj < 8; ++fj) {
          float kf = __uint_as_float((__float_as_uint(acc[mi][fj][r]) & KMASK) |
                                     (unsigned)(codebase + fj * 16));
          M2 = fminf(M2, fmaxf(M1, kf));
          M1 = fminf(M1, kf);
        }
        m1s[mi][r] = M1; m2s[mi][r] = M2;
      }
    }
  }

  // cell = split*32 + wcN*16 + col  (64 codes: ct 8 x fj 8)
  const int cell = split * 32 + wcN * 16 + l15;
#pragma unroll
  for (int mi = 0; mi < 4; ++mi) {
#pragma unroll
    for (int r = 0; r < 4; ++r) {
      int token = tb * 256 + wrM * 64 + mi * 16 + (lane >> 4) * 4 + r;
      float2* p = (float2*)(slotbuf + (size_t)token * 256);
      p[cell] = make_float2(m1s[mi][r], m2s[mi][r]);
    }
  }
}

// one wave per token; exact f64 re-rank of margin candidates
__global__ void k_select(const float* __restrict__ slotbuf, const float* __restrict__ z,
                         const float* __restrict__ w, int* __restrict__ idxb,
                         unsigned int* __restrict__ counts) {
  const int lane = threadIdx.x & 63;
  const int t = blockIdx.x * 4 + (threadIdx.x >> 6);

  float4 e = *(const float4*)(slotbuf + (size_t)t * 256 + lane * 4);
  float p0 = e.x, p1 = e.y, p2 = e.z, p3 = e.w;  // cells 2*lane (m1,m2), 2*lane+1 (m1,m2)
  float pk = fminf(fminf(p0, p1), fminf(p2, p3));
#pragma unroll
  for (int m = 1; m < 64; m <<= 1) pk = fminf(pk, __shfl_xor(pk, m));
  const unsigned int mb = __float_as_uint(pk);
  int best = (int)(mb & 0x1FFFu);
  const float thr = __uint_as_float(mb & 0xFFFFE000u) + MARGIN;

  const unsigned int KM = 0xFFFFE000u;
  bool f0 = __uint_as_float(__float_as_uint(p0) & KM) < thr;
  bool f1 = __uint_as_float(__float_as_uint(p1) & KM) < thr;
  bool f2 = __uint_as_float(__float_as_uint(p2) & KM) < thr;
  bool f3 = __uint_as_float(__float_as_uint(p3) & KM) < thr;
  unsigned long long b0 = __ballot(f0), b1 = __ballot(f1);
  unsigned long long b2 = __ballot(f2), b3 = __ballot(f3);
  int nc = __popcll(b0) + __popcll(b1) + __popcll(b2) + __popcll(b3);

  if (nc > 1) {
    const float4* zp = (const float4*)(z + (size_t)t * DIM) + lane * 2;
    float4 za = zp[0], zc = zp[1];
    double bestd = 1e300;
    int besti = NE;

    auto eval = [&](int code) {
      const float4* wp = (const float4*)(w + (size_t)code * DIM) + lane * 2;
      float4 wa = wp[0], wv2 = wp[1];
      double d = (double)wa.x * ((double)wa.x - 2.0 * (double)za.x)
               + (double)wa.y * ((double)wa.y - 2.0 * (double)za.y)
               + (double)wa.z * ((double)wa.z - 2.0 * (double)za.z)
               + (double)wa.w * ((double)wa.w - 2.0 * (double)za.w)
               + (double)wv2.x * ((double)wv2.x - 2.0 * (double)zc.x)
               + (double)wv2.y * ((double)wv2.y - 2.0 * (double)zc.y)
               + (double)wv2.z * ((double)wv2.z - 2.0 * (double)zc.z)
               + (double)wv2.w * ((double)wv2.w - 2.0 * (double)zc.w);
#pragma unroll
      for (int m = 1; m < 64; m <<= 1) d += __shfl_xor(d, m);
      if (d < bestd || (d == bestd && code < besti)) { bestd = d; besti = code; }
    };
    // cell = (split, wcN, col): codes sp*2048 + ct*256 + wcN*128 + fj*16 + col
    auto scan_cell = [&](int cid) {
      int sp = cid >> 5, wcc = (cid >> 4) & 1, col = cid & 15;
      int base = sp * 2048 + wcc * 128 + col;
      for (int ctt = 0; ctt < 8; ++ctt)
        for (int fj = 0; fj < 8; ++fj)
          eval(base + ctt * 256 + fj * 16);
    };

    int i0 = (int)(__float_as_uint(p0) & 0x1FFFu);
    int i1 = (int)(__float_as_uint(p1) & 0x1FFFu);
    int i2 = (int)(__float_as_uint(p2) & 0x1FFFu);
    int i3 = (int)(__float_as_uint(p3) & 0x1FFFu);
    unsigned long long bm;
    bm = b0; while (bm) { int s = __ffsll(bm) - 1; bm &= bm - 1; eval(__shfl(i0, s)); }
    bm = b1; while (bm) { int s = __ffsll(bm) - 1; bm &= bm - 1; eval(__shfl(i1, s)); }
    bm = b2; while (bm) { int s = __ffsll(bm) - 1; bm &= bm - 1; eval(__shfl(i2, s)); }
    bm = b3; while (bm) { int s = __ffsll(bm) - 1; bm &= bm - 1; eval(__shfl(i3, s)); }
    unsigned long long h0 = __ballot(f0 && f1);
    unsigned long long h1 = __ballot(f2 && f3);
    bm = h0; while (bm) { int s = __ffsll(bm) - 1; bm &= bm - 1; scan_cell(2 * s); }
    bm = h1; while (bm) { int s = __ffsll(bm) - 1; bm &= bm - 1; scan_cell(2 * s + 1); }
    best = besti;
  }
  if (lane == 0) {
    idxb[t] = best;
    atomicAdd(&counts[best], 1u);
  }
}

__global__ void k_gather(const float* __restrict__ w, const int* __restrict__ idxb,
                         float* __restrict__ out) {
  int n = blockIdx.x * 2 + (threadIdx.x >> 7);
  int j = threadIdx.x & 127;
  int k = idxb[n];
  ((float4*)out)[(size_t)n * 128 + j] = ((const float4*)w)[(size_t)k * 128 + j];
}

__global__ void k_perp(const unsigned int* __restrict__ counts, float* __restrict__ out) {
  __shared__ float red[16];
  float s = 0.f;
  for (int k = threadIdx.x; k < NE; k += 1024) {
    float p = (float)counts[k] * (1.0f / (float)NTOK);
    s += p * logf(p + 1e-10f);
  }
#pragma unroll
  for (int m = 1; m < 64; m <<= 1) s += __shfl_xor(s, m);
  int lane = threadIdx.x & 63, wv = threadIdx.x >> 6;
  if (lane == 0) red[wv] = s;
  __syncthreads();
  if (threadIdx.x == 0) {
    float tot = 0.f;
    for (int i = 0; i < 16; ++i) tot += red[i];
    out[(size_t)NTOK * DIM] = expf(-tot);
  }
}

extern "C" void kernel_launch(void* const* d_in, const int* in_sizes, int n_in,
                              void* d_out, int out_size, void* d_ws, size_t ws_size,
                              hipStream_t stream) {
  const float* z = (const float*)d_in[0];
  const float* w = (const float*)d_in[1];
  float* out = (float*)d_out;
  char* ws = (char*)d_ws;

  unsigned int* zb      = (unsigned int*)(ws);
  unsigned int* wb      = (unsigned int*)(ws + 33554432);
  float*        cnorm   = (float*)(ws + 41943040);
  float*        slotbuf = (float*)(ws + 41975808);
  int*          idxb    = (int*)(ws + 75530240);
  unsigned int* counts  = (unsigned int*)(ws + 75661312);

  k_prep_z<<<8192, 256, 0, stream>>>(z, zb);
  k_prep_w<<<2048, 256, 0, stream>>>(w, wb, cnorm);
  k_phase1<<<512, 512, 0, stream>>>((const unsigned short*)zb, (const unsigned short*)wb,
                                    cnorm, slotbuf);
  hipMemsetAsync(counts, 0, NE * sizeof(unsigned int), stream);
  k_select<<<8192, 256, 0, stream>>>(slotbuf, z, w, idxb, counts);
  k_gather<<<16384, 256, 0, stream>>>(w, idxb, out);
  k_perp<<<1, 1024, 0, stream>>>(counts, out);
}

// Round 8
// 413.147 us; speedup vs baseline: 1.4406x; 1.1005x over previous
//
#include <hip/hip_runtime.h>
#include <stdint.h>

// VectorQuantizer: z[32768,512] f32, weight[8192,512] f32 ->
//   out[0 .. 32768*512) = z_q = weight[argmin_k ||z-e_k||^2]  (exact fp32 rows)
//   out[32768*512]      = perplexity
//
// Pipeline:
//  1) k_prep_z: bf16(-2z); k_prep_w: bf16(w) + exact f32 row norms c_k
//  2) k_phase1: 128x128 tile, 4 waves (2x2, wave 64x64), BK=32, DOUBLE-buffered
//     2x16KB LDS (32KB total -> 2 blocks/CU for cross-block stall filling),
//     counted vmcnt(4) (1-step prefetch), 2 raw barriers/step, setprio.
//     cnorm folded into first MFMA's C operand (kc=0 peeled) -> d = c - 2 z.e.
//     Per token: top-2 packed keys (quantized d | 13-bit code) per 128 cells
//     (cell = (split,wc,col); 64 codes each = 16ct x 4fj) -> slotbuf
//  3) k_select: global min; margin candidates re-ranked with exact f64 dots
//     (cells with both entries in margin fully rescanned); idx + histogram
//  4) k_gather: z_q rows ; k_perp: perplexity
//
// ws layout (bytes): zb@0 32MB | wb@33554432 8MB | cnorm@41943040 32KB |
//   slot@41975808 32MB | idx@75530240 128KB | counts@75661312 32KB

#define NTOK 32768
#define NE   8192
#define DIM  512
#define MARGIN 4.0f

typedef __attribute__((ext_vector_type(8))) short bf16x8;
typedef __attribute__((ext_vector_type(4))) float f32x4;

#define SBAR   __builtin_amdgcn_s_barrier()
#define SCHED0 __builtin_amdgcn_sched_barrier(0)

__device__ __forceinline__ unsigned int f2bf1(float x) {
  unsigned int u = __float_as_uint(x);
  return (u + 0x7FFFu + ((u >> 16) & 1u)) >> 16;
}
__device__ __forceinline__ unsigned int packbf2(float lo, float hi) {
  return f2bf1(lo) | (f2bf1(hi) << 16);
}

__device__ __forceinline__ void gl_lds16(const void* g, void* l) {
  __builtin_amdgcn_global_load_lds(
      (const __attribute__((address_space(1))) void*)g,
      (__attribute__((address_space(3))) void*)l, 16, 0, 0);
}

__global__ void k_prep_z(const float* __restrict__ z, unsigned int* __restrict__ zb) {
  int i = blockIdx.x * 256 + threadIdx.x;  // one thread per 8 floats
  const float4* zp = (const float4*)z + (size_t)i * 2;
  float4 a = zp[0], b = zp[1];
  uint4 o;  // store bf16(-2z): exact 2x scaling, same rounding as bf16(z)
  o.x = packbf2(-2.f * a.x, -2.f * a.y); o.y = packbf2(-2.f * a.z, -2.f * a.w);
  o.z = packbf2(-2.f * b.x, -2.f * b.y); o.w = packbf2(-2.f * b.z, -2.f * b.w);
  ((uint4*)zb)[i] = o;
}

__global__ void k_prep_w(const float* __restrict__ w, unsigned int* __restrict__ wb,
                         float* __restrict__ cnorm) {
  int row  = blockIdx.x * 4 + (threadIdx.x >> 6);  // one wave per code row
  int lane = threadIdx.x & 63;
  const float4* wp = (const float4*)(w + (size_t)row * DIM) + lane * 2;
  float4 a = wp[0], b = wp[1];
  uint4 o;
  o.x = packbf2(a.x, a.y); o.y = packbf2(a.z, a.w);
  o.z = packbf2(b.x, b.y); o.w = packbf2(b.z, b.w);
  ((uint4*)wb)[(size_t)row * 64 + lane] = o;
  float s = a.x * a.x + a.y * a.y + a.z * a.z + a.w * a.w
          + b.x * b.x + b.y * b.y + b.z * b.z + b.w * b.w;
#pragma unroll
  for (int m = 1; m < 64; m <<= 1) s += __shfl_xor(s, m);
  if (lane == 0) cnorm[row] = s;
}

// 256 thr = 4 waves (wr,wc in 2x2), tile 128 tok x 128 codes, wave 64x64.
// BK=32 (64B LDS rows, slot-XOR swizzle), dbuf 2x16KB, vmcnt(4), 2 SBAR/step.
// grid 1024 = 256 tb x 4 splits (2048 codes = 16 ct x 128), XCD-chunked.
__global__ void __launch_bounds__(256) k_phase1(
    const unsigned short* __restrict__ zb, const unsigned short* __restrict__ wb,
    const float* __restrict__ cnorm, float* __restrict__ slotbuf) {
  __shared__ char S[2][16384];  // [buf][A: 128 rows x 64B | B: 128 rows x 64B]

  const int tid  = threadIdx.x;
  const int lane = tid & 63;
  const int wv   = tid >> 6;
  const int wr   = wv >> 1;
  const int wc   = wv & 1;
  const int swzb  = (blockIdx.x & 7) * 128 + (blockIdx.x >> 3);
  const int split = swzb >> 8;   // 0..3
  const int tb    = swzb & 255;  // 0..255
  const int l15  = lane & 15;

  // 64B-row swizzle (r6-proven): element (row, 16B-slot c) stored at slot
  // c ^ ((row>>1)&3). Staging: lane l -> row += l>>2, dest slot l&3, so
  // source slot = (l&3) ^ ((l>>3)&3)   [(row>>1)&3 == (l>>3)&3].
  const int srcsw = (((lane & 3) ^ ((lane >> 3) & 3)) << 4);
  const char* zsA = (const char*)zb + (size_t)(tb * 128 + wv * 32 + (lane >> 2)) * 1024 + srcsw;
  const char* zsB = (const char*)wb + (size_t)(split * 2048 + wv * 32 + (lane >> 2)) * 1024 + srcsw;

  // Frag read: k-group g=lane>>4 wants slot g of row base+l15 ->
  // stored slot g ^ ((lane>>1)&3)  [row bases are 0 mod 16].
  const int rdsw = ((((lane >> 4) ^ (lane >> 1)) & 3) << 4);
  int arow[4], brow[4];
#pragma unroll
  for (int i = 0; i < 4; ++i) {
    arow[i] = (wr * 64 + i * 16 + l15) * 64 + rdsw;
    brow[i] = 8192 + (wc * 64 + i * 16 + l15) * 64 + rdsw;
  }

  const float BIG = 3.0e38f;
  float m1s[4][4], m2s[4][4];
#pragma unroll
  for (int mi = 0; mi < 4; ++mi)
#pragma unroll
    for (int r = 0; r < 4; ++r) { m1s[mi][r] = BIG; m2s[mi][r] = BIG; }

  const unsigned int KMASK = 0xFFFFE000u;

  // stage K-tile g into buf g&1 (4 gl_lds per wave: A 2, B 2; 1KB each)
  auto stage = [&](int g) {
    char* DA = &S[g & 1][wv * 2048];
    const char* ga = zsA + ((g & 15) << 6);
    gl_lds16(ga, DA);
    gl_lds16(ga + 16 * 1024, DA + 1024);
    char* DB = &S[g & 1][8192 + wv * 2048];
    const char* gb = zsB + ((g >> 4) << 17) + ((g & 15) << 6);
    gl_lds16(gb, DB);
    gl_lds16(gb + 16 * 1024, DB + 1024);
  };

  stage(0);
  __syncthreads();  // drains prologue; queue clean

  for (int ct = 0; ct < 16; ++ct) {
    const int codebase = split * 2048 + ct * 128 + wc * 64 + l15;
    // cf loads: drained by the entry vmcnt(4) of kc=0 (they are older)
    float cf0 = cnorm[codebase + 0];
    float cf1 = cnorm[codebase + 16];
    float cf2 = cnorm[codebase + 32];
    float cf3 = cnorm[codebase + 48];
    f32x4 acc[4][4];

    // ---- kc = 0 (peeled): init acc via C-operand = ||e||^2
    {
      const int g = ct * 16;
      stage(g + 1);
      asm volatile("s_waitcnt vmcnt(4)" ::: "memory");
      SBAR; SCHED0;
      const char* P = S[g & 1];
      bf16x8 a[4], b[4];
#pragma unroll
      for (int i = 0; i < 4; ++i) { a[i] = *(const bf16x8*)(P + arow[i]); b[i] = *(const bf16x8*)(P + brow[i]); }
      f32x4 c0 = {cf0, cf0, cf0, cf0}, c1 = {cf1, cf1, cf1, cf1};
      f32x4 c2 = {cf2, cf2, cf2, cf2}, c3 = {cf3, cf3, cf3, cf3};
      __builtin_amdgcn_s_setprio(1);
#pragma unroll
      for (int mi = 0; mi < 4; ++mi) {
        acc[mi][0] = __builtin_amdgcn_mfma_f32_16x16x32_bf16(a[mi], b[0], c0, 0, 0, 0);
        acc[mi][1] = __builtin_amdgcn_mfma_f32_16x16x32_bf16(a[mi], b[1], c1, 0, 0, 0);
        acc[mi][2] = __builtin_amdgcn_mfma_f32_16x16x32_bf16(a[mi], b[2], c2, 0, 0, 0);
        acc[mi][3] = __builtin_amdgcn_mfma_f32_16x16x32_bf16(a[mi], b[3], c3, 0, 0, 0);
      }
      __builtin_amdgcn_s_setprio(0);
      SBAR;
    }

    // ---- kc = 1..15
    for (int kc = 1; kc < 16; ++kc) {
      const int g = ct * 16 + kc;
      if (g < 255) { stage(g + 1); asm volatile("s_waitcnt vmcnt(4)" ::: "memory"); }
      else         { asm volatile("s_waitcnt vmcnt(0)" ::: "memory"); }
      SBAR; SCHED0;
      const char* P = S[g & 1];
      bf16x8 a[4], b[4];
#pragma unroll
      for (int i = 0; i < 4; ++i) { a[i] = *(const bf16x8*)(P + arow[i]); b[i] = *(const bf16x8*)(P + brow[i]); }
      __builtin_amdgcn_s_setprio(1);
#pragma unroll
      for (int mi = 0; mi < 4; ++mi)
#pragma unroll
        for (int fj = 0; fj < 4; ++fj)
          acc[mi][fj] = __builtin_amdgcn_mfma_f32_16x16x32_bf16(a[mi], b[fj], acc[mi][fj], 0, 0, 0);
      __builtin_amdgcn_s_setprio(0);
      SBAR;  // reads of buf g&1 done -> tile g+2 may overwrite
    }

    // epilogue: acc IS d = c - 2 z.e ; pack (quantized d | code), top-2 merge
#pragma unroll
    for (int mi = 0; mi < 4; ++mi) {
#pragma unroll
      for (int r = 0; r < 4; ++r) {
        float k0 = __uint_as_float((__float_as_uint(acc[mi][0][r]) & KMASK) | (unsigned)(codebase + 0));
        float k1 = __uint_as_float((__float_as_uint(acc[mi][1][r]) & KMASK) | (unsigned)(codebase + 16));
        float k2 = __uint_as_float((__float_as_uint(acc[mi][2][r]) & KMASK) | (unsigned)(codebase + 32));
        float k3 = __uint_as_float((__float_as_uint(acc[mi][3][r]) & KMASK) | (unsigned)(codebase + 48));
        float lo01 = fminf(k0, k1), hi01 = fmaxf(k0, k1);
        float lo23 = fminf(k2, k3), hi23 = fmaxf(k2, k3);
        float a1 = fminf(lo01, lo23);
        float a2 = fminf(fmaxf(lo01, lo23), fminf(hi01, hi23));
        float M1 = m1s[mi][r], M2 = m2s[mi][r];
        m2s[mi][r] = fminf(fminf(M2, a2), fmaxf(M1, a1));
        m1s[mi][r] = fminf(M1, a1);
      }
    }
  }

  // cell = split*32 + wc*16 + col  (64 codes: 16 ct x 4 fj)
  const int cell = split * 32 + wc * 16 + l15;
#pragma unroll
  for (int mi = 0; mi < 4; ++mi) {
#pragma unroll
    for (int r = 0; r < 4; ++r) {
      int token = tb * 128 + wr * 64 + mi * 16 + (lane >> 4) * 4 + r;
      float2* p = (float2*)(slotbuf + (size_t)token * 256);
      p[cell] = make_float2(m1s[mi][r], m2s[mi][r]);
    }
  }
}

// one wave per token; exact f64 re-rank of margin candidates
__global__ void k_select(const float* __restrict__ slotbuf, const float* __restrict__ z,
                         const float* __restrict__ w, int* __restrict__ idxb,
                         unsigned int* __restrict__ counts) {
  const int lane = threadIdx.x & 63;
  const int t = blockIdx.x * 4 + (threadIdx.x >> 6);

  float4 e = *(const float4*)(slotbuf + (size_t)t * 256 + lane * 4);
  float p0 = e.x, p1 = e.y, p2 = e.z, p3 = e.w;  // cells 2*lane (m1,m2), 2*lane+1 (m1,m2)
  float pk = fminf(fminf(p0, p1), fminf(p2, p3));
#pragma unroll
  for (int m = 1; m < 64; m <<= 1) pk = fminf(pk, __shfl_xor(pk, m));
  const unsigned int mb = __float_as_uint(pk);
  int best = (int)(mb & 0x1FFFu);
  const float thr = __uint_as_float(mb & 0xFFFFE000u) + MARGIN;

  const unsigned int KM = 0xFFFFE000u;
  bool f0 = __uint_as_float(__float_as_uint(p0) & KM) < thr;
  bool f1 = __uint_as_float(__float_as_uint(p1) & KM) < thr;
  bool f2 = __uint_as_float(__float_as_uint(p2) & KM) < thr;
  bool f3 = __uint_as_float(__float_as_uint(p3) & KM) < thr;
  unsigned long long b0 = __ballot(f0), b1 = __ballot(f1);
  unsigned long long b2 = __ballot(f2), b3 = __ballot(f3);
  int nc = __popcll(b0) + __popcll(b1) + __popcll(b2) + __popcll(b3);

  if (nc > 1) {
    const float4* zp = (const float4*)(z + (size_t)t * DIM) + lane * 2;
    float4 za = zp[0], zc = zp[1];
    double bestd = 1e300;
    int besti = NE;

    auto eval = [&](int code) {
      const float4* wp = (const float4*)(w + (size_t)code * DIM) + lane * 2;
      float4 wa = wp[0], wv2 = wp[1];
      double d = (double)wa.x * ((double)wa.x - 2.0 * (double)za.x)
               + (double)wa.y * ((double)wa.y - 2.0 * (double)za.y)
               + (double)wa.z * ((double)wa.z - 2.0 * (double)za.z)
               + (double)wa.w * ((double)wa.w - 2.0 * (double)za.w)
               + (double)wv2.x * ((double)wv2.x - 2.0 * (double)zc.x)
               + (double)wv2.y * ((double)wv2.y - 2.0 * (double)zc.y)
               + (double)wv2.z * ((double)wv2.z - 2.0 * (double)zc.z)
               + (double)wv2.w * ((double)wv2.w - 2.0 * (double)zc.w);
#pragma unroll
      for (int m = 1; m < 64; m <<= 1) d += __shfl_xor(d, m);
      if (d < bestd || (d == bestd && code < besti)) { bestd = d; besti = code; }
    };
    // cell = (split, wc, col): codes sp*2048 + ct*128 + wcc*64 + nf*16 + col
    auto scan_cell = [&](int cid) {
      int sp = cid >> 5, wcc = (cid >> 4) & 1, col = cid & 15;
      int base = sp * 2048 + wcc * 64 + col;
      for (int ctt = 0; ctt < 16; ++ctt)
        for (int nf = 0; nf < 4; ++nf)
          eval(base + ctt * 128 + nf * 16);
    };

    int i0 = (int)(__float_as_uint(p0) & 0x1FFFu);
    int i1 = (int)(__float_as_uint(p1) & 0x1FFFu);
    int i2 = (int)(__float_as_uint(p2) & 0x1FFFu);
    int i3 = (int)(__float_as_uint(p3) & 0x1FFFu);
    unsigned long long bm;
    bm = b0; while (bm) { int s = __ffsll(bm) - 1; bm &= bm - 1; eval(__shfl(i0, s)); }
    bm = b1; while (bm) { int s = __ffsll(bm) - 1; bm &= bm - 1; eval(__shfl(i1, s)); }
    bm = b2; while (bm) { int s = __ffsll(bm) - 1; bm &= bm - 1; eval(__shfl(i2, s)); }
    bm = b3; while (bm) { int s = __ffsll(bm) - 1; bm &= bm - 1; eval(__shfl(i3, s)); }
    unsigned long long h0 = __ballot(f0 && f1);
    unsigned long long h1 = __ballot(f2 && f3);
    bm = h0; while (bm) { int s = __ffsll(bm) - 1; bm &= bm - 1; scan_cell(2 * s); }
    bm = h1; while (bm) { int s = __ffsll(bm) - 1; bm &= bm - 1; scan_cell(2 * s + 1); }
    best = besti;
  }
  if (lane == 0) {
    idxb[t] = best;
    atomicAdd(&counts[best], 1u);
  }
}

__global__ void k_gather(const float* __restrict__ w, const int* __restrict__ idxb,
                         float* __restrict__ out) {
  int n = blockIdx.x * 2 + (threadIdx.x >> 7);
  int j = threadIdx.x & 127;
  int k = idxb[n];
  ((float4*)out)[(size_t)n * 128 + j] = ((const float4*)w)[(size_t)k * 128 + j];
}

__global__ void k_perp(const unsigned int* __restrict__ counts, float* __restrict__ out) {
  __shared__ float red[16];
  float s = 0.f;
  for (int k = threadIdx.x; k < NE; k += 1024) {
    float p = (float)counts[k] * (1.0f / (float)NTOK);
    s += p * logf(p + 1e-10f);
  }
#pragma unroll
  for (int m = 1; m < 64; m <<= 1) s += __shfl_xor(s, m);
  int lane = threadIdx.x & 63, wv = threadIdx.x >> 6;
  if (lane == 0) red[wv] = s;
  __syncthreads();
  if (threadIdx.x == 0) {
    float tot = 0.f;
    for (int i = 0; i < 16; ++i) tot += red[i];
    out[(size_t)NTOK * DIM] = expf(-tot);
  }
}

extern "C" void kernel_launch(void* const* d_in, const int* in_sizes, int n_in,
                              void* d_out, int out_size, void* d_ws, size_t ws_size,
                              hipStream_t stream) {
  const float* z = (const float*)d_in[0];
  const float* w = (const float*)d_in[1];
  float* out = (float*)d_out;
  char* ws = (char*)d_ws;

  unsigned int* zb      = (unsigned int*)(ws);
  unsigned int* wb      = (unsigned int*)(ws + 33554432);
  float*        cnorm   = (float*)(ws + 41943040);
  float*        slotbuf = (float*)(ws + 41975808);
  int*          idxb    = (int*)(ws + 75530240);
  unsigned int* counts  = (unsigned int*)(ws + 75661312);

  k_prep_z<<<8192, 256, 0, stream>>>(z, zb);
  k_prep_w<<<2048, 256, 0, stream>>>(w, wb, cnorm);
  k_phase1<<<1024, 256, 0, stream>>>((const unsigned short*)zb, (const unsigned short*)wb,
                                     cnorm, slotbuf);
  hipMemsetAsync(counts, 0, NE * sizeof(unsigned int), stream);
  k_select<<<8192, 256, 0, stream>>>(slotbuf, z, w, idxb, counts);
  k_gather<<<16384, 256, 0, stream>>>(w, idxb, out);
  k_perp<<<1, 1024, 0, stream>>>(counts, out);
}

// Round 9
// 388.023 us; speedup vs baseline: 1.5339x; 1.0647x over previous
//
#include <hip/hip_runtime.h>
#include <stdint.h>

// VectorQuantizer: z[32768,512] f32, weight[8192,512] f32 ->
//   out[0 .. 32768*512) = z_q = weight[argmin_k ||z-e_k||^2]  (exact fp32 rows)
//   out[32768*512]      = perplexity
//
// Pipeline:
//  1) k_prep_z: bf16(-2z); k_prep_w: bf16(w) + exact f32 row norms c_k
//  2) k_phase1: 128x256 tile, 4 waves (2M x 2N), wave tile 64x128 (4x8 frags
//     -> LDS-read : MFMA cycles balanced ~1:1), BK=32, dbuf 2x24KB LDS,
//     counted vmcnt(6), 2 raw barriers/step, setprio. cnorm folded into
//     first MFMA's C operand (kc=0 peeled) -> d = c - 2 z.e directly.
//     Per token: top-2 packed keys (quantized d | 13-bit code) per 128 cells
//     (cell = (split,wcN,col); 64 codes each = 8ct x 8fj) -> slotbuf
//  3) k_select: global min; margin candidates re-ranked with exact f64 dots
//     (cells with both entries in margin fully rescanned); idx + histogram
//  4) k_gather: z_q rows ; k_perp: perplexity
//
// ws layout (bytes): zb@0 32MB | wb@33554432 8MB | cnorm@41943040 32KB |
//   slot@41975808 32MB | idx@75530240 128KB | counts@75661312 32KB

#define NTOK 32768
#define NE   8192
#define DIM  512
#define MARGIN 4.0f

typedef __attribute__((ext_vector_type(8))) short bf16x8;
typedef __attribute__((ext_vector_type(4))) float f32x4;

#define SBAR   __builtin_amdgcn_s_barrier()
#define SCHED0 __builtin_amdgcn_sched_barrier(0)

__device__ __forceinline__ unsigned int f2bf1(float x) {
  unsigned int u = __float_as_uint(x);
  return (u + 0x7FFFu + ((u >> 16) & 1u)) >> 16;
}
__device__ __forceinline__ unsigned int packbf2(float lo, float hi) {
  return f2bf1(lo) | (f2bf1(hi) << 16);
}

__device__ __forceinline__ void gl_lds16(const void* g, void* l) {
  __builtin_amdgcn_global_load_lds(
      (const __attribute__((address_space(1))) void*)g,
      (__attribute__((address_space(3))) void*)l, 16, 0, 0);
}

__global__ void k_prep_z(const float* __restrict__ z, unsigned int* __restrict__ zb) {
  int i = blockIdx.x * 256 + threadIdx.x;  // one thread per 8 floats
  const float4* zp = (const float4*)z + (size_t)i * 2;
  float4 a = zp[0], b = zp[1];
  uint4 o;  // store bf16(-2z): exact 2x scaling, same rounding as bf16(z)
  o.x = packbf2(-2.f * a.x, -2.f * a.y); o.y = packbf2(-2.f * a.z, -2.f * a.w);
  o.z = packbf2(-2.f * b.x, -2.f * b.y); o.w = packbf2(-2.f * b.z, -2.f * b.w);
  ((uint4*)zb)[i] = o;
}

__global__ void k_prep_w(const float* __restrict__ w, unsigned int* __restrict__ wb,
                         float* __restrict__ cnorm) {
  int row  = blockIdx.x * 4 + (threadIdx.x >> 6);  // one wave per code row
  int lane = threadIdx.x & 63;
  const float4* wp = (const float4*)(w + (size_t)row * DIM) + lane * 2;
  float4 a = wp[0], b = wp[1];
  uint4 o;
  o.x = packbf2(a.x, a.y); o.y = packbf2(a.z, a.w);
  o.z = packbf2(b.x, b.y); o.w = packbf2(b.z, b.w);
  ((uint4*)wb)[(size_t)row * 64 + lane] = o;
  float s = a.x * a.x + a.y * a.y + a.z * a.z + a.w * a.w
          + b.x * b.x + b.y * b.y + b.z * b.z + b.w * b.w;
#pragma unroll
  for (int m = 1; m < 64; m <<= 1) s += __shfl_xor(s, m);
  if (lane == 0) cnorm[row] = s;
}

// 256 thr = 4 waves: wrM=wv>>1 (token half), wcN=wv&1 (code half).
// Block tile 128 tok x 256 codes; wave tile 64x128 = 4mi x 8fj frags.
// BK=32 (64B rows, slot-XOR swizzle), dbuf 2x24KB, vmcnt(6), 2 SBAR/step.
// grid 1024 = 256 tb x 4 splits (2048 codes = 8 ct x 256), XCD-chunked.
__global__ void __launch_bounds__(256, 2) k_phase1(
    const unsigned short* __restrict__ zb, const unsigned short* __restrict__ wb,
    const float* __restrict__ cnorm, float* __restrict__ slotbuf) {
  __shared__ char S[2][24576];  // [buf][A: 128 rows x 64B | B: 256 rows x 64B]

  const int tid  = threadIdx.x;
  const int lane = tid & 63;
  const int wv   = tid >> 6;
  const int wrM  = wv >> 1;
  const int wcN  = wv & 1;
  const int swzb  = (blockIdx.x & 7) * 128 + (blockIdx.x >> 3);
  const int split = swzb >> 8;   // 0..3
  const int tb    = swzb & 255;  // 0..255
  const int l15  = lane & 15;

  // 64B-row swizzle (r6/r8-proven): element (row, 16B-slot c) stored at slot
  // c ^ ((row>>1)&3). Staging: lane l -> row += l>>2, dest slot l&3 ->
  // source slot = (l&3) ^ ((l>>3)&3).
  const int srcsw = (((lane & 3) ^ ((lane >> 3) & 3)) << 4);
  const char* zsA = (const char*)zb + (size_t)(tb * 128 + wv * 32 + (lane >> 2)) * 1024 + srcsw;
  const char* zsB = (const char*)wb + (size_t)(split * 2048 + wv * 64 + (lane >> 2)) * 1024 + srcsw;

  // Frag read: k-group g=lane>>4 wants slot g of row base+l15 ->
  // stored slot g ^ ((lane>>1)&3)  [row bases are 0 mod 16].
  const int rdsw = ((((lane >> 4) ^ (lane >> 1)) & 3) << 4);
  int arow[4], brow[8];
#pragma unroll
  for (int mi = 0; mi < 4; ++mi) arow[mi] = (wrM * 64 + mi * 16 + l15) * 64 + rdsw;
#pragma unroll
  for (int fj = 0; fj < 8; ++fj) brow[fj] = 8192 + (wcN * 128 + fj * 16 + l15) * 64 + rdsw;

  const float BIG = 3.0e38f;
  float m1s[4][4], m2s[4][4];
#pragma unroll
  for (int mi = 0; mi < 4; ++mi)
#pragma unroll
    for (int r = 0; r < 4; ++r) { m1s[mi][r] = BIG; m2s[mi][r] = BIG; }

  const unsigned int KMASK = 0xFFFFE000u;

  // stage K-tile g into buf g&1: A 2 loads (32 rows/wave), B 4 loads (64 rows)
  auto stage = [&](int g) {
    char* DA = &S[g & 1][wv * 2048];
    const char* ga = zsA + ((g & 15) << 6);
    gl_lds16(ga, DA);
    gl_lds16(ga + 16 * 1024, DA + 1024);
    char* DB = &S[g & 1][8192 + wv * 4096];
    const char* gb = zsB + ((g >> 4) << 18) + ((g & 15) << 6);
    gl_lds16(gb, DB);
    gl_lds16(gb + 16 * 1024, DB + 1024);
    gl_lds16(gb + 32 * 1024, DB + 2048);
    gl_lds16(gb + 48 * 1024, DB + 3072);
  };

  stage(0);
  __syncthreads();  // drains prologue; queue clean

  for (int ct = 0; ct < 8; ++ct) {
    const int codebase = split * 2048 + ct * 256 + wcN * 128 + l15;
    // cf loads: older than stage(g+1) -> drained by kc=0's vmcnt(6)
    float cf[8];
#pragma unroll
    for (int fj = 0; fj < 8; ++fj) cf[fj] = cnorm[codebase + fj * 16];
    f32x4 acc[4][8];

    // ---- kc = 0 (peeled): init acc via C-operand = ||e||^2
    {
      const int g = ct * 16;
      stage(g + 1);
      asm volatile("s_waitcnt vmcnt(6)" ::: "memory");
      SBAR; SCHED0;
      const char* P = S[g & 1];
      bf16x8 a[4], b[8];
#pragma unroll
      for (int i = 0; i < 4; ++i) a[i] = *(const bf16x8*)(P + arow[i]);
#pragma unroll
      for (int j = 0; j < 8; ++j) b[j] = *(const bf16x8*)(P + brow[j]);
      __builtin_amdgcn_s_setprio(1);
#pragma unroll
      for (int mi = 0; mi < 4; ++mi)
#pragma unroll
        for (int fj = 0; fj < 8; ++fj) {
          f32x4 c = {cf[fj], cf[fj], cf[fj], cf[fj]};
          acc[mi][fj] = __builtin_amdgcn_mfma_f32_16x16x32_bf16(a[mi], b[fj], c, 0, 0, 0);
        }
      __builtin_amdgcn_s_setprio(0);
      SBAR;
    }

    // ---- kc = 1..15
    for (int kc = 1; kc < 16; ++kc) {
      const int g = ct * 16 + kc;
      if (g < 127) { stage(g + 1); asm volatile("s_waitcnt vmcnt(6)" ::: "memory"); }
      else         { asm volatile("s_waitcnt vmcnt(0)" ::: "memory"); }
      SBAR; SCHED0;
      const char* P = S[g & 1];
      bf16x8 a[4], b[8];
#pragma unroll
      for (int i = 0; i < 4; ++i) a[i] = *(const bf16x8*)(P + arow[i]);
#pragma unroll
      for (int j = 0; j < 8; ++j) b[j] = *(const bf16x8*)(P + brow[j]);
      __builtin_amdgcn_s_setprio(1);
#pragma unroll
      for (int mi = 0; mi < 4; ++mi)
#pragma unroll
        for (int fj = 0; fj < 8; ++fj)
          acc[mi][fj] = __builtin_amdgcn_mfma_f32_16x16x32_bf16(a[mi], b[fj], acc[mi][fj], 0, 0, 0);
      __builtin_amdgcn_s_setprio(0);
      SBAR;  // reads of buf g&1 done -> tile g+2 may overwrite
    }

    // epilogue: acc IS d = c - 2 z.e ; pack (quantized d | code), top-2 insert
#pragma unroll
    for (int mi = 0; mi < 4; ++mi) {
#pragma unroll
      for (int r = 0; r < 4; ++r) {
        float M1 = m1s[mi][r], M2 = m2s[mi][r];
#pragma unroll
        for (int fj = 0; fj < 8; ++fj) {
          float kf = __uint_as_float((__float_as_uint(acc[mi][fj][r]) & KMASK) |
                                     (unsigned)(codebase + fj * 16));
          M2 = fminf(M2, fmaxf(M1, kf));
          M1 = fminf(M1, kf);
        }
        m1s[mi][r] = M1; m2s[mi][r] = M2;
      }
    }
  }

  // cell = split*32 + wcN*16 + col  (64 codes: 8 ct x 8 fj)
  const int cell = split * 32 + wcN * 16 + l15;
#pragma unroll
  for (int mi = 0; mi < 4; ++mi) {
#pragma unroll
    for (int r = 0; r < 4; ++r) {
      int token = tb * 128 + wrM * 64 + mi * 16 + (lane >> 4) * 4 + r;
      float2* p = (float2*)(slotbuf + (size_t)token * 256);
      p[cell] = make_float2(m1s[mi][r], m2s[mi][r]);
    }
  }
}

// one wave per token; exact f64 re-rank of margin candidates
__global__ void k_select(const float* __restrict__ slotbuf, const float* __restrict__ z,
                         const float* __restrict__ w, int* __restrict__ idxb,
                         unsigned int* __restrict__ counts) {
  const int lane = threadIdx.x & 63;
  const int t = blockIdx.x * 4 + (threadIdx.x >> 6);

  float4 e = *(const float4*)(slotbuf + (size_t)t * 256 + lane * 4);
  float p0 = e.x, p1 = e.y, p2 = e.z, p3 = e.w;  // cells 2*lane (m1,m2), 2*lane+1 (m1,m2)
  float pk = fminf(fminf(p0, p1), fminf(p2, p3));
#pragma unroll
  for (int m = 1; m < 64; m <<= 1) pk = fminf(pk, __shfl_xor(pk, m));
  const unsigned int mb = __float_as_uint(pk);
  int best = (int)(mb & 0x1FFFu);
  const float thr = __uint_as_float(mb & 0xFFFFE000u) + MARGIN;

  const unsigned int KM = 0xFFFFE000u;
  bool f0 = __uint_as_float(__float_as_uint(p0) & KM) < thr;
  bool f1 = __uint_as_float(__float_as_uint(p1) & KM) < thr;
  bool f2 = __uint_as_float(__float_as_uint(p2) & KM) < thr;
  bool f3 = __uint_as_float(__float_as_uint(p3) & KM) < thr;
  unsigned long long b0 = __ballot(f0), b1 = __ballot(f1);
  unsigned long long b2 = __ballot(f2), b3 = __ballot(f3);
  int nc = __popcll(b0) + __popcll(b1) + __popcll(b2) + __popcll(b3);

  if (nc > 1) {
    const float4* zp = (const float4*)(z + (size_t)t * DIM) + lane * 2;
    float4 za = zp[0], zc = zp[1];
    double bestd = 1e300;
    int besti = NE;

    auto eval = [&](int code) {
      const float4* wp = (const float4*)(w + (size_t)code * DIM) + lane * 2;
      float4 wa = wp[0], wv2 = wp[1];
      double d = (double)wa.x * ((double)wa.x - 2.0 * (double)za.x)
               + (double)wa.y * ((double)wa.y - 2.0 * (double)za.y)
               + (double)wa.z * ((double)wa.z - 2.0 * (double)za.z)
               + (double)wa.w * ((double)wa.w - 2.0 * (double)za.w)
               + (double)wv2.x * ((double)wv2.x - 2.0 * (double)zc.x)
               + (double)wv2.y * ((double)wv2.y - 2.0 * (double)zc.y)
               + (double)wv2.z * ((double)wv2.z - 2.0 * (double)zc.z)
               + (double)wv2.w * ((double)wv2.w - 2.0 * (double)zc.w);
#pragma unroll
      for (int m = 1; m < 64; m <<= 1) d += __shfl_xor(d, m);
      if (d < bestd || (d == bestd && code < besti)) { bestd = d; besti = code; }
    };
    // cell = (split, wcN, col): codes sp*2048 + ct*256 + wcN*128 + fj*16 + col
    auto scan_cell = [&](int cid) {
      int sp = cid >> 5, wcc = (cid >> 4) & 1, col = cid & 15;
      int base = sp * 2048 + wcc * 128 + col;
      for (int ctt = 0; ctt < 8; ++ctt)
        for (int fj = 0; fj < 8; ++fj)
          eval(base + ctt * 256 + fj * 16);
    };

    int i0 = (int)(__float_as_uint(p0) & 0x1FFFu);
    int i1 = (int)(__float_as_uint(p1) & 0x1FFFu);
    int i2 = (int)(__float_as_uint(p2) & 0x1FFFu);
    int i3 = (int)(__float_as_uint(p3) & 0x1FFFu);
    unsigned long long bm;
    bm = b0; while (bm) { int s = __ffsll(bm) - 1; bm &= bm - 1; eval(__shfl(i0, s)); }
    bm = b1; while (bm) { int s = __ffsll(bm) - 1; bm &= bm - 1; eval(__shfl(i1, s)); }
    bm = b2; while (bm) { int s = __ffsll(bm) - 1; bm &= bm - 1; eval(__shfl(i2, s)); }
    bm = b3; while (bm) { int s = __ffsll(bm) - 1; bm &= bm - 1; eval(__shfl(i3, s)); }
    unsigned long long h0 = __ballot(f0 && f1);
    unsigned long long h1 = __ballot(f2 && f3);
    bm = h0; while (bm) { int s = __ffsll(bm) - 1; bm &= bm - 1; scan_cell(2 * s); }
    bm = h1; while (bm) { int s = __ffsll(bm) - 1; bm &= bm - 1; scan_cell(2 * s + 1); }
    best = besti;
  }
  if (lane == 0) {
    idxb[t] = best;
    atomicAdd(&counts[best], 1u);
  }
}

__global__ void k_gather(const float* __restrict__ w, const int* __restrict__ idxb,
                         float* __restrict__ out) {
  int n = blockIdx.x * 2 + (threadIdx.x >> 7);
  int j = threadIdx.x & 127;
  int k = idxb[n];
  ((float4*)out)[(size_t)n * 128 + j] = ((const float4*)w)[(size_t)k * 128 + j];
}

__global__ void k_perp(const unsigned int* __restrict__ counts, float* __restrict__ out) {
  __shared__ float red[16];
  float s = 0.f;
  for (int k = threadIdx.x; k < NE; k += 1024) {
    float p = (float)counts[k] * (1.0f / (float)NTOK);
    s += p * logf(p + 1e-10f);
  }
#pragma unroll
  for (int m = 1; m < 64; m <<= 1) s += __shfl_xor(s, m);
  int lane = threadIdx.x & 63, wv = threadIdx.x >> 6;
  if (lane == 0) red[wv] = s;
  __syncthreads();
  if (threadIdx.x == 0) {
    float tot = 0.f;
    for (int i = 0; i < 16; ++i) tot += red[i];
    out[(size_t)NTOK * DIM] = expf(-tot);
  }
}

extern "C" void kernel_launch(void* const* d_in, const int* in_sizes, int n_in,
                              void* d_out, int out_size, void* d_ws, size_t ws_size,
                              hipStream_t stream) {
  const float* z = (const float*)d_in[0];
  const float* w = (const float*)d_in[1];
  float* out = (float*)d_out;
  char* ws = (char*)d_ws;

  unsigned int* zb      = (unsigned int*)(ws);
  unsigned int* wb      = (unsigned int*)(ws + 33554432);
  float*        cnorm   = (float*)(ws + 41943040);
  float*        slotbuf = (float*)(ws + 41975808);
  int*          idxb    = (int*)(ws + 75530240);
  unsigned int* counts  = (unsigned int*)(ws + 75661312);

  k_prep_z<<<8192, 256, 0, stream>>>(z, zb);
  k_prep_w<<<2048, 256, 0, stream>>>(w, wb, cnorm);
  k_phase1<<<1024, 256, 0, stream>>>((const unsigned short*)zb, (const unsigned short*)wb,
                                     cnorm, slotbuf);
  hipMemsetAsync(counts, 0, NE * sizeof(unsigned int), stream);
  k_select<<<8192, 256, 0, stream>>>(slotbuf, z, w, idxb, counts);
  k_gather<<<16384, 256, 0, stream>>>(w, idxb, out);
  k_perp<<<1, 1024, 0, stream>>>(counts, out);
}

// Round 10
// 376.327 us; speedup vs baseline: 1.5815x; 1.0311x over previous
//
#include <hip/hip_runtime.h>
#include <stdint.h>

// VectorQuantizer: z[32768,512] f32, weight[8192,512] f32 ->
//   out[0 .. 32768*512) = z_q = weight[argmin_k ||z-e_k||^2]  (exact fp32 rows)
//   out[32768*512]      = perplexity
//
// Pipeline (MX-fp8 round):
//  1) k_prep_z: e4m3(-2z); k_prep_w: e4m3(w) + exact f32 row norms c_k
//  2) k_phase1: 128x128 tile, 4 waves (2x2, wave 64x64 = 4mi x 4fj frags of
//     mfma_scale_f32_16x16x128_f8f6f4 with UNIFORM scale 2^0 (0x7F bytes) ->
//     fp8 matmul at the 2x MX rate. K-step=128 (128B LDS rows, slot-XOR
//     swizzle), dbuf 2x32KB, counted vmcnt(8), 2 raw barriers/step, setprio.
//     acc init = ||e||^2 via C operand (kc=0 peeled) -> d~ = c - 2 z.e.
//     Per token: top-2 packed keys (quantized d | 13-bit code) per 128 cells
//     (cell = (split,wc,col); 64 codes = 16ct x 4fj) -> slotbuf
//  3) k_select: global min; MARGIN=16 (fp8 d-err sigma~2.3) candidates
//     re-ranked with exact f64 dots (hot cells rescanned); idx + histogram
//  4) k_gather: z_q rows ; k_perp: perplexity
//
// ws layout (bytes): zb@0 16MB | wb@33554432 4MB | cnorm@41943040 32KB |
//   slot@41975808 32MB | idx@75530240 128KB | counts@75661312 32KB

#define NTOK 32768
#define NE   8192
#define DIM  512
#define MARGIN 16.0f

typedef __attribute__((ext_vector_type(8))) int   v8i;
typedef __attribute__((ext_vector_type(4))) float f32x4;

#define SBAR   __builtin_amdgcn_s_barrier()
#define SCHED0 __builtin_amdgcn_sched_barrier(0)
#define SCALE1 0x7F7F7F7F  // e8m0 biased-127 = 2^0 in every byte

__device__ __forceinline__ void gl_lds16(const void* g, void* l) {
  __builtin_amdgcn_global_load_lds(
      (const __attribute__((address_space(1))) void*)g,
      (__attribute__((address_space(3))) void*)l, 16, 0, 0);
}

__device__ __forceinline__ int pk8(float a, float b, float c, float d) {
  int r = __builtin_amdgcn_cvt_pk_fp8_f32(a, b, 0, false);
  return __builtin_amdgcn_cvt_pk_fp8_f32(c, d, r, true);
}

__global__ void k_prep_z(const float* __restrict__ z, int2* __restrict__ zb) {
  int i = blockIdx.x * 256 + threadIdx.x;  // one thread per 8 floats
  const float4* zp = (const float4*)z + (size_t)i * 2;
  float4 a = zp[0], b = zp[1];
  int2 o;  // e4m3(-2z)
  o.x = pk8(-2.f * a.x, -2.f * a.y, -2.f * a.z, -2.f * a.w);
  o.y = pk8(-2.f * b.x, -2.f * b.y, -2.f * b.z, -2.f * b.w);
  zb[i] = o;
}

__global__ void k_prep_w(const float* __restrict__ w, int2* __restrict__ wb,
                         float* __restrict__ cnorm) {
  int row  = blockIdx.x * 4 + (threadIdx.x >> 6);  // one wave per code row
  int lane = threadIdx.x & 63;
  const float4* wp = (const float4*)(w + (size_t)row * DIM) + lane * 2;
  float4 a = wp[0], b = wp[1];
  int2 o;
  o.x = pk8(a.x, a.y, a.z, a.w);
  o.y = pk8(b.x, b.y, b.z, b.w);
  wb[(size_t)row * 64 + lane] = o;
  float s = a.x * a.x + a.y * a.y + a.z * a.z + a.w * a.w
          + b.x * b.x + b.y * b.y + b.z * b.z + b.w * b.w;
#pragma unroll
  for (int m = 1; m < 64; m <<= 1) s += __shfl_xor(s, m);
  if (lane == 0) cnorm[row] = s;
}

// 256 thr = 4 waves (wr,wc 2x2), tile 128 tok x 128 codes, wave 64x64.
// K-step 128 (fp8): rows 128B (8 x 16B slots), slot-XOR swizzle c^(row&7).
// dbuf 2x32KB; 8 gl_lds/wave/step; vmcnt(8); 64 K-steps total (16ct x 4kc).
// grid 1024 = 256 tb x 4 splits, XCD-chunked bijective swizzle.
__global__ void __launch_bounds__(256) k_phase1(
    const unsigned char* __restrict__ zb, const unsigned char* __restrict__ wb,
    const float* __restrict__ cnorm, float* __restrict__ slotbuf) {
  __shared__ char S[2][32768];  // [buf][A: 128 rows x 128B | B: 128 rows x 128B]

  const int tid  = threadIdx.x;
  const int lane = tid & 63;
  const int wv   = tid >> 6;
  const int wr   = wv >> 1;
  const int wc   = wv & 1;
  const int swzb  = (blockIdx.x & 7) * 128 + (blockIdx.x >> 3);
  const int split = swzb >> 8;   // 0..3
  const int tb    = swzb & 255;  // 0..255
  const int l15  = lane & 15;

  // staging: lane l -> dest row l>>3, slot l&7; swizzled store slot = c^(row&7)
  // => pre-swizzled source slot = (l&7) ^ ((l>>3)&7).
  const int srcsw = (((lane & 7) ^ ((lane >> 3) & 7)) << 4);
  const unsigned char* zsA = zb + (size_t)(tb * 128 + wv * 32 + (lane >> 3)) * 512 + srcsw;
  const unsigned char* zsB = wb + (size_t)(split * 2048 + wv * 32 + (lane >> 3)) * 512 + srcsw;

  // frag reads: lane wants slots {2g, 2g+1} (g = lane>>4) of row base+l15;
  // stored slot = want ^ (row&7), row&7 == lane&7 (bases are 0 mod 16).
  const int offs0 = ((((lane >> 4) * 2) ^ (lane & 7)) << 4);
  const int offs1 = ((((lane >> 4) * 2 + 1) ^ (lane & 7)) << 4);
  int arow[4], brow[4];
#pragma unroll
  for (int i = 0; i < 4; ++i) {
    arow[i] = (wr * 64 + i * 16 + l15) * 128;
    brow[i] = 16384 + (wc * 64 + i * 16 + l15) * 128;
  }

  const float BIG = 3.0e38f;
  float m1s[4][4], m2s[4][4];
#pragma unroll
  for (int mi = 0; mi < 4; ++mi)
#pragma unroll
    for (int r = 0; r < 4; ++r) { m1s[mi][r] = BIG; m2s[mi][r] = BIG; }

  const unsigned int KMASK = 0xFFFFE000u;

  // stage K-step g (g = ct*4+kc) into buf g&1: A 4 + B 4 gl_lds per wave
  auto stage = [&](int g) {
    char* DA = &S[g & 1][wv * 4096];
    const unsigned char* ga = zsA + ((g & 3) << 7);
#pragma unroll
    for (int r = 0; r < 4; ++r) gl_lds16(ga + r * 4096, DA + r * 1024);
    char* DB = &S[g & 1][16384 + wv * 4096];
    const unsigned char* gb = zsB + ((size_t)(g >> 2) << 16) + ((g & 3) << 7);
#pragma unroll
    for (int r = 0; r < 4; ++r) gl_lds16(gb + r * 4096, DB + r * 1024);
  };

  auto mk8 = [](const char* p) {
    int4 lo = *(const int4*)p;
    return lo;
  };

  stage(0);
  __syncthreads();  // drains prologue; queue clean

  for (int ct = 0; ct < 16; ++ct) {
    const int codebase = split * 2048 + ct * 128 + wc * 64 + l15;
    // cf loads are older than stage(g+1) -> drained by kc=0's vmcnt(8)
    float cf0 = cnorm[codebase + 0];
    float cf1 = cnorm[codebase + 16];
    float cf2 = cnorm[codebase + 32];
    float cf3 = cnorm[codebase + 48];
    f32x4 acc[4][4];

#pragma unroll 1
    for (int kc = 0; kc < 4; ++kc) {
      const int g = ct * 4 + kc;
      if (g < 63) { stage(g + 1); asm volatile("s_waitcnt vmcnt(8)" ::: "memory"); }
      else        { asm volatile("s_waitcnt vmcnt(0)" ::: "memory"); }
      SBAR; SCHED0;
      const char* P = S[g & 1];
      v8i a[4], b[4];
#pragma unroll
      for (int i = 0; i < 4; ++i) {
        int4 alo = *(const int4*)(P + arow[i] + offs0);
        int4 ahi = *(const int4*)(P + arow[i] + offs1);
        v8i av; av[0]=alo.x; av[1]=alo.y; av[2]=alo.z; av[3]=alo.w;
        av[4]=ahi.x; av[5]=ahi.y; av[6]=ahi.z; av[7]=ahi.w;
        a[i] = av;
        int4 blo = *(const int4*)(P + brow[i] + offs0);
        int4 bhi = *(const int4*)(P + brow[i] + offs1);
        v8i bv; bv[0]=blo.x; bv[1]=blo.y; bv[2]=blo.z; bv[3]=blo.w;
        bv[4]=bhi.x; bv[5]=bhi.y; bv[6]=bhi.z; bv[7]=bhi.w;
        b[i] = bv;
      }
      __builtin_amdgcn_s_setprio(1);
      if (kc == 0) {
        f32x4 c0 = {cf0, cf0, cf0, cf0}, c1 = {cf1, cf1, cf1, cf1};
        f32x4 c2 = {cf2, cf2, cf2, cf2}, c3 = {cf3, cf3, cf3, cf3};
#pragma unroll
        for (int mi = 0; mi < 4; ++mi) {
          acc[mi][0] = __builtin_amdgcn_mfma_scale_f32_16x16x128_f8f6f4(a[mi], b[0], c0, 0, 0, 0, SCALE1, 0, SCALE1);
          acc[mi][1] = __builtin_amdgcn_mfma_scale_f32_16x16x128_f8f6f4(a[mi], b[1], c1, 0, 0, 0, SCALE1, 0, SCALE1);
          acc[mi][2] = __builtin_amdgcn_mfma_scale_f32_16x16x128_f8f6f4(a[mi], b[2], c2, 0, 0, 0, SCALE1, 0, SCALE1);
          acc[mi][3] = __builtin_amdgcn_mfma_scale_f32_16x16x128_f8f6f4(a[mi], b[3], c3, 0, 0, 0, SCALE1, 0, SCALE1);
        }
      } else {
#pragma unroll
        for (int mi = 0; mi < 4; ++mi)
#pragma unroll
          for (int fj = 0; fj < 4; ++fj)
            acc[mi][fj] = __builtin_amdgcn_mfma_scale_f32_16x16x128_f8f6f4(a[mi], b[fj], acc[mi][fj], 0, 0, 0, SCALE1, 0, SCALE1);
      }
      __builtin_amdgcn_s_setprio(0);
      SBAR;  // reads of buf g&1 done -> step g+2 may overwrite
    }

    // epilogue: acc IS d~ = c - 2 z.e ; pack (quantized d | code), top-2 merge
#pragma unroll
    for (int mi = 0; mi < 4; ++mi) {
#pragma unroll
      for (int r = 0; r < 4; ++r) {
        float k0 = __uint_as_float((__float_as_uint(acc[mi][0][r]) & KMASK) | (unsigned)(codebase + 0));
        float k1 = __uint_as_float((__float_as_uint(acc[mi][1][r]) & KMASK) | (unsigned)(codebase + 16));
        float k2 = __uint_as_float((__float_as_uint(acc[mi][2][r]) & KMASK) | (unsigned)(codebase + 32));
        float k3 = __uint_as_float((__float_as_uint(acc[mi][3][r]) & KMASK) | (unsigned)(codebase + 48));
        float lo01 = fminf(k0, k1), hi01 = fmaxf(k0, k1);
        float lo23 = fminf(k2, k3), hi23 = fmaxf(k2, k3);
        float a1 = fminf(lo01, lo23);
        float a2 = fminf(fmaxf(lo01, lo23), fminf(hi01, hi23));
        float M1 = m1s[mi][r], M2 = m2s[mi][r];
        m2s[mi][r] = fminf(fminf(M2, a2), fmaxf(M1, a1));
        m1s[mi][r] = fminf(M1, a1);
      }
    }
  }

  // cell = split*32 + wc*16 + col  (64 codes: 16 ct x 4 fj)
  const int cell = split * 32 + wc * 16 + l15;
#pragma unroll
  for (int mi = 0; mi < 4; ++mi) {
#pragma unroll
    for (int r = 0; r < 4; ++r) {
      int token = tb * 128 + wr * 64 + mi * 16 + (lane >> 4) * 4 + r;
      float2* p = (float2*)(slotbuf + (size_t)token * 256);
      p[cell] = make_float2(m1s[mi][r], m2s[mi][r]);
    }
  }
}

// one wave per token; exact f64 re-rank of margin candidates
__global__ void k_select(const float* __restrict__ slotbuf, const float* __restrict__ z,
                         const float* __restrict__ w, int* __restrict__ idxb,
                         unsigned int* __restrict__ counts) {
  const int lane = threadIdx.x & 63;
  const int t = blockIdx.x * 4 + (threadIdx.x >> 6);

  float4 e = *(const float4*)(slotbuf + (size_t)t * 256 + lane * 4);
  float p0 = e.x, p1 = e.y, p2 = e.z, p3 = e.w;  // cells 2*lane (m1,m2), 2*lane+1 (m1,m2)
  float pk = fminf(fminf(p0, p1), fminf(p2, p3));
#pragma unroll
  for (int m = 1; m < 64; m <<= 1) pk = fminf(pk, __shfl_xor(pk, m));
  const unsigned int mb = __float_as_uint(pk);
  int best = (int)(mb & 0x1FFFu);
  const float thr = __uint_as_float(mb & 0xFFFFE000u) + MARGIN;

  const unsigned int KM = 0xFFFFE000u;
  bool f0 = __uint_as_float(__float_as_uint(p0) & KM) < thr;
  bool f1 = __uint_as_float(__float_as_uint(p1) & KM) < thr;
  bool f2 = __uint_as_float(__float_as_uint(p2) & KM) < thr;
  bool f3 = __uint_as_float(__float_as_uint(p3) & KM) < thr;
  unsigned long long b0 = __ballot(f0), b1 = __ballot(f1);
  unsigned long long b2 = __ballot(f2), b3 = __ballot(f3);
  int nc = __popcll(b0) + __popcll(b1) + __popcll(b2) + __popcll(b3);

  if (nc > 1) {
    const float4* zp = (const float4*)(z + (size_t)t * DIM) + lane * 2;
    float4 za = zp[0], zc = zp[1];
    double bestd = 1e300;
    int besti = NE;

    auto eval = [&](int code) {
      const float4* wp = (const float4*)(w + (size_t)code * DIM) + lane * 2;
      float4 wa = wp[0], wv2 = wp[1];
      double d = (double)wa.x * ((double)wa.x - 2.0 * (double)za.x)
               + (double)wa.y * ((double)wa.y - 2.0 * (double)za.y)
               + (double)wa.z * ((double)wa.z - 2.0 * (double)za.z)
               + (double)wa.w * ((double)wa.w - 2.0 * (double)za.w)
               + (double)wv2.x * ((double)wv2.x - 2.0 * (double)zc.x)
               + (double)wv2.y * ((double)wv2.y - 2.0 * (double)zc.y)
               + (double)wv2.z * ((double)wv2.z - 2.0 * (double)zc.z)
               + (double)wv2.w * ((double)wv2.w - 2.0 * (double)zc.w);
#pragma unroll
      for (int m = 1; m < 64; m <<= 1) d += __shfl_xor(d, m);
      if (d < bestd || (d == bestd && code < besti)) { bestd = d; besti = code; }
    };
    // cell = (split, wc, col): codes sp*2048 + ct*128 + wcc*64 + nf*16 + col
    auto scan_cell = [&](int cid) {
      int sp = cid >> 5, wcc = (cid >> 4) & 1, col = cid & 15;
      int base = sp * 2048 + wcc * 64 + col;
      for (int ctt = 0; ctt < 16; ++ctt)
        for (int nf = 0; nf < 4; ++nf)
          eval(base + ctt * 128 + nf * 16);
    };

    int i0 = (int)(__float_as_uint(p0) & 0x1FFFu);
    int i1 = (int)(__float_as_uint(p1) & 0x1FFFu);
    int i2 = (int)(__float_as_uint(p2) & 0x1FFFu);
    int i3 = (int)(__float_as_uint(p3) & 0x1FFFu);
    unsigned long long bm;
    bm = b0; while (bm) { int s = __ffsll(bm) - 1; bm &= bm - 1; eval(__shfl(i0, s)); }
    bm = b1; while (bm) { int s = __ffsll(bm) - 1; bm &= bm - 1; eval(__shfl(i1, s)); }
    bm = b2; while (bm) { int s = __ffsll(bm) - 1; bm &= bm - 1; eval(__shfl(i2, s)); }
    bm = b3; while (bm) { int s = __ffsll(bm) - 1; bm &= bm - 1; eval(__shfl(i3, s)); }
    unsigned long long h0 = __ballot(f0 && f1);
    unsigned long long h1 = __ballot(f2 && f3);
    bm = h0; while (bm) { int s = __ffsll(bm) - 1; bm &= bm - 1; scan_cell(2 * s); }
    bm = h1; while (bm) { int s = __ffsll(bm) - 1; bm &= bm - 1; scan_cell(2 * s + 1); }
    best = besti;
  }
  if (lane == 0) {
    idxb[t] = best;
    atomicAdd(&counts[best], 1u);
  }
}

__global__ void k_gather(const float* __restrict__ w, const int* __restrict__ idxb,
                         float* __restrict__ out) {
  int n = blockIdx.x * 2 + (threadIdx.x >> 7);
  int j = threadIdx.x & 127;
  int k = idxb[n];
  ((float4*)out)[(size_t)n * 128 + j] = ((const float4*)w)[(size_t)k * 128 + j];
}

__global__ void k_perp(const unsigned int* __restrict__ counts, float* __restrict__ out) {
  __shared__ float red[16];
  float s = 0.f;
  for (int k = threadIdx.x; k < NE; k += 1024) {
    float p = (float)counts[k] * (1.0f / (float)NTOK);
    s += p * logf(p + 1e-10f);
  }
#pragma unroll
  for (int m = 1; m < 64; m <<= 1) s += __shfl_xor(s, m);
  int lane = threadIdx.x & 63, wv = threadIdx.x >> 6;
  if (lane == 0) red[wv] = s;
  __syncthreads();
  if (threadIdx.x == 0) {
    float tot = 0.f;
    for (int i = 0; i < 16; ++i) tot += red[i];
    out[(size_t)NTOK * DIM] = expf(-tot);
  }
}

extern "C" void kernel_launch(void* const* d_in, const int* in_sizes, int n_in,
                              void* d_out, int out_size, void* d_ws, size_t ws_size,
                              hipStream_t stream) {
  const float* z = (const float*)d_in[0];
  const float* w = (const float*)d_in[1];
  float* out = (float*)d_out;
  char* ws = (char*)d_ws;

  unsigned char* zb     = (unsigned char*)(ws);
  unsigned char* wb     = (unsigned char*)(ws + 33554432);
  float*        cnorm   = (float*)(ws + 41943040);
  float*        slotbuf = (float*)(ws + 41975808);
  int*          idxb    = (int*)(ws + 75530240);
  unsigned int* counts  = (unsigned int*)(ws + 75661312);

  k_prep_z<<<8192, 256, 0, stream>>>(z, (int2*)zb);
  k_prep_w<<<2048, 256, 0, stream>>>(w, (int2*)wb, cnorm);
  k_phase1<<<1024, 256, 0, stream>>>(zb, wb, cnorm, slotbuf);
  hipMemsetAsync(counts, 0, NE * sizeof(unsigned int), stream);
  k_select<<<8192, 256, 0, stream>>>(slotbuf, z, w, idxb, counts);
  k_gather<<<16384, 256, 0, stream>>>(w, idxb, out);
  k_perp<<<1, 1024, 0, stream>>>(counts, out);
}

// Round 11
// 306.126 us; speedup vs baseline: 1.9442x; 1.2293x over previous
//
#include <hip/hip_runtime.h>
#include <stdint.h>

// VectorQuantizer: z[32768,512] f32, weight[8192,512] f32 ->
//   out[0 .. 32768*512) = z_q = weight[argmin_k ||z-e_k||^2]  (exact fp32 rows)
//   out[32768*512]      = perplexity
//
// Pipeline (MX-fp8, conflict-free LDS planes, top-3 cells):
//  1) k_prep_z: e4m3(-2z); k_prep_w: e4m3(w) + exact f32 row norms c_k
//  2) k_phase1: 128x128 tile, 4 waves, mfma_scale_f32_16x16x128_f8f6f4 with
//     uniform scale 2^0. LDS: fp8 128B rows stored as TWO 64B half-row planes
//     (r9's measured-zero-conflict geometry: slot ^ ((row>>1)&3), alternating
//     row-start banks). dbuf 2x32KB, counted vmcnt(8), 2 barriers/step,
//     setprio. acc init = ||e||^2 via C operand -> d~ = c - 2 z.e.
//     Per token: TOP-3 packed keys (quantized d | 13-bit code) per 128 cells
//     (cell = (split,wc,col); 64 codes = 16ct x 4fj) -> slot2 (m1,m2) + slot3.
//  3) k_select: global min; MARGIN=16 candidates (m1/m2 direct, full 64-code
//     rescan only if m3 in margin) re-ranked with exact f64 dots; histogram;
//     writes z_q row directly (gather merged).
//  4) k_perp: perplexity
//
// ws layout (bytes): zb@0 16MB | slot3@16777216 16MB | wb@33554432 4MB |
//   cnorm@41943040 32KB | slot2@41975808 32MB | counts@75661312 32KB

#define NTOK 32768
#define NE   8192
#define DIM  512
#define MARGIN 16.0f

typedef __attribute__((ext_vector_type(8))) int   v8i;
typedef __attribute__((ext_vector_type(4))) float f32x4;

#define SBAR   __builtin_amdgcn_s_barrier()
#define SCHED0 __builtin_amdgcn_sched_barrier(0)
#define SCALE1 0x7F7F7F7F  // e8m0 biased-127 = 2^0 in every byte

__device__ __forceinline__ void gl_lds16(const void* g, void* l) {
  __builtin_amdgcn_global_load_lds(
      (const __attribute__((address_space(1))) void*)g,
      (__attribute__((address_space(3))) void*)l, 16, 0, 0);
}

__device__ __forceinline__ int pk8(float a, float b, float c, float d) {
  int r = __builtin_amdgcn_cvt_pk_fp8_f32(a, b, 0, false);
  return __builtin_amdgcn_cvt_pk_fp8_f32(c, d, r, true);
}

__global__ void k_prep_z(const float* __restrict__ z, int2* __restrict__ zb) {
  int i = blockIdx.x * 256 + threadIdx.x;  // one thread per 8 floats
  const float4* zp = (const float4*)z + (size_t)i * 2;
  float4 a = zp[0], b = zp[1];
  int2 o;  // e4m3(-2z)
  o.x = pk8(-2.f * a.x, -2.f * a.y, -2.f * a.z, -2.f * a.w);
  o.y = pk8(-2.f * b.x, -2.f * b.y, -2.f * b.z, -2.f * b.w);
  zb[i] = o;
}

__global__ void k_prep_w(const float* __restrict__ w, int2* __restrict__ wb,
                         float* __restrict__ cnorm) {
  int row  = blockIdx.x * 4 + (threadIdx.x >> 6);  // one wave per code row
  int lane = threadIdx.x & 63;
  const float4* wp = (const float4*)(w + (size_t)row * DIM) + lane * 2;
  float4 a = wp[0], b = wp[1];
  int2 o;
  o.x = pk8(a.x, a.y, a.z, a.w);
  o.y = pk8(b.x, b.y, b.z, b.w);
  wb[(size_t)row * 64 + lane] = o;
  float s = a.x * a.x + a.y * a.y + a.z * a.z + a.w * a.w
          + b.x * b.x + b.y * b.y + b.z * b.z + b.w * b.w;
#pragma unroll
  for (int m = 1; m < 64; m <<= 1) s += __shfl_xor(s, m);
  if (lane == 0) cnorm[row] = s;
}

// 256 thr = 4 waves (wr,wc 2x2), tile 128 tok x 128 codes, wave 64x64.
// K-step 128 fp8 stored as 2 planes of [128 rows][64B]; swizzle slot^((row>>1)&3).
// dbuf 2x32KB; 8 gl_lds/wave/step; vmcnt(8); 64 K-steps (16ct x 4kc).
// grid 1024 = 256 tb x 4 splits, XCD-chunked bijective swizzle.
__global__ void __launch_bounds__(256) k_phase1(
    const unsigned char* __restrict__ zb, const unsigned char* __restrict__ wb,
    const float* __restrict__ cnorm, float* __restrict__ slot2,
    float* __restrict__ slot3) {
  __shared__ char S[2][32768];  // [buf][ A: 2 planes x 8KB | B: 2 planes x 8KB ]

  const int tid  = threadIdx.x;
  const int lane = tid & 63;
  const int wv   = tid >> 6;
  const int wr   = wv >> 1;
  const int wc   = wv & 1;
  const int swzb  = (blockIdx.x & 7) * 128 + (blockIdx.x >> 3);
  const int split = swzb >> 8;   // 0..3
  const int tb    = swzb & 255;  // 0..255
  const int l15  = lane & 15;

  // staging: issue (t,h): lane l -> plane h, row wv*32+t*16+(l>>2), slot l&3;
  // stored slot = c ^ ((row>>1)&3) -> source slot = (l&3)^((l>>3)&3).
  const int srcsw = (((lane & 3) ^ ((lane >> 3) & 3)) << 4);
  const unsigned char* zsA = zb + (size_t)(tb * 128 + wv * 32 + (lane >> 2)) * 512 + srcsw;
  const unsigned char* zsB = wb + (size_t)(split * 2048 + wv * 32 + (lane >> 2)) * 512 + srcsw;

  // frag reads: k-group g=lane>>4 -> plane h=g>>1, slots {2(g&1), 2(g&1)+1},
  // stored ^((row>>1)&3) = ^((lane>>1)&3)  [row bases are 0 mod 16].
  const int g    = lane >> 4;
  const int key  = (lane >> 1) & 3;
  const int offs0 = (g >> 1) * 8192 + (((2 * (g & 1)) ^ key) << 4);
  const int offs1 = (g >> 1) * 8192 + (((2 * (g & 1) + 1) ^ key) << 4);
  int arow[4], brow[4];
#pragma unroll
  for (int i = 0; i < 4; ++i) {
    arow[i] = (wr * 64 + i * 16 + l15) * 64;
    brow[i] = 16384 + (wc * 64 + i * 16 + l15) * 64;
  }

  const float BIG = 3.0e38f;
  float m1s[4][4], m2s[4][4], m3s[4][4];
#pragma unroll
  for (int mi = 0; mi < 4; ++mi)
#pragma unroll
    for (int r = 0; r < 4; ++r) { m1s[mi][r] = BIG; m2s[mi][r] = BIG; m3s[mi][r] = BIG; }

  const unsigned int KMASK = 0xFFFFE000u;

  // stage K-step gg (= ct*4+kc) into buf gg&1: A 4 + B 4 issues per wave
  auto stage = [&](int gg) {
    const int kc = gg & 3, ct2 = gg >> 2;
    char* base = S[gg & 1];
    const unsigned char* ga = zsA + kc * 128;
    char* da = base + wv * 2048;
    gl_lds16(ga,             da);                 // t0 h0
    gl_lds16(ga + 64,        da + 8192);          // t0 h1
    gl_lds16(ga + 8192,      da + 1024);          // t1 h0
    gl_lds16(ga + 8192 + 64, da + 8192 + 1024);   // t1 h1
    const unsigned char* gb = zsB + ct2 * 65536 + kc * 128;
    char* db = base + 16384 + wv * 2048;
    gl_lds16(gb,             db);
    gl_lds16(gb + 64,        db + 8192);
    gl_lds16(gb + 8192,      db + 1024);
    gl_lds16(gb + 8192 + 64, db + 8192 + 1024);
  };

  stage(0);
  __syncthreads();  // drains prologue; queue clean

  for (int ct = 0; ct < 16; ++ct) {
    const int codebase = split * 2048 + ct * 128 + wc * 64 + l15;
    // cf loads are older than stage(gg+1) -> drained by kc=0's vmcnt(8)
    float cf0 = cnorm[codebase + 0];
    float cf1 = cnorm[codebase + 16];
    float cf2 = cnorm[codebase + 32];
    float cf3 = cnorm[codebase + 48];
    f32x4 acc[4][4];

#pragma unroll 1
    for (int kc = 0; kc < 4; ++kc) {
      const int gg = ct * 4 + kc;
      if (gg < 63) { stage(gg + 1); asm volatile("s_waitcnt vmcnt(8)" ::: "memory"); }
      else         { asm volatile("s_waitcnt vmcnt(0)" ::: "memory"); }
      SBAR; SCHED0;
      const char* P = S[gg & 1];
      v8i a[4], b[4];
#pragma unroll
      for (int i = 0; i < 4; ++i) {
        int4 alo = *(const int4*)(P + arow[i] + offs0);
        int4 ahi = *(const int4*)(P + arow[i] + offs1);
        v8i av; av[0]=alo.x; av[1]=alo.y; av[2]=alo.z; av[3]=alo.w;
        av[4]=ahi.x; av[5]=ahi.y; av[6]=ahi.z; av[7]=ahi.w;
        a[i] = av;
        int4 blo = *(const int4*)(P + brow[i] + offs0);
        int4 bhi = *(const int4*)(P + brow[i] + offs1);
        v8i bv; bv[0]=blo.x; bv[1]=blo.y; bv[2]=blo.z; bv[3]=blo.w;
        bv[4]=bhi.x; bv[5]=bhi.y; bv[6]=bhi.z; bv[7]=bhi.w;
        b[i] = bv;
      }
      __builtin_amdgcn_s_setprio(1);
      if (kc == 0) {
        f32x4 c0 = {cf0, cf0, cf0, cf0}, c1 = {cf1, cf1, cf1, cf1};
        f32x4 c2 = {cf2, cf2, cf2, cf2}, c3 = {cf3, cf3, cf3, cf3};
#pragma unroll
        for (int mi = 0; mi < 4; ++mi) {
          acc[mi][0] = __builtin_amdgcn_mfma_scale_f32_16x16x128_f8f6f4(a[mi], b[0], c0, 0, 0, 0, SCALE1, 0, SCALE1);
          acc[mi][1] = __builtin_amdgcn_mfma_scale_f32_16x16x128_f8f6f4(a[mi], b[1], c1, 0, 0, 0, SCALE1, 0, SCALE1);
          acc[mi][2] = __builtin_amdgcn_mfma_scale_f32_16x16x128_f8f6f4(a[mi], b[2], c2, 0, 0, 0, SCALE1, 0, SCALE1);
          acc[mi][3] = __builtin_amdgcn_mfma_scale_f32_16x16x128_f8f6f4(a[mi], b[3], c3, 0, 0, 0, SCALE1, 0, SCALE1);
        }
      } else {
#pragma unroll
        for (int mi = 0; mi < 4; ++mi)
#pragma unroll
          for (int fj = 0; fj < 4; ++fj)
            acc[mi][fj] = __builtin_amdgcn_mfma_scale_f32_16x16x128_f8f6f4(a[mi], b[fj], acc[mi][fj], 0, 0, 0, SCALE1, 0, SCALE1);
      }
      __builtin_amdgcn_s_setprio(0);
      SBAR;  // reads of buf gg&1 done -> step gg+2 may overwrite
    }

    // epilogue: acc IS d~ = c - 2 z.e ; pack (quantized d | code), top-3 insert
#pragma unroll
    for (int mi = 0; mi < 4; ++mi) {
#pragma unroll
      for (int r = 0; r < 4; ++r) {
        float M1 = m1s[mi][r], M2 = m2s[mi][r], M3 = m3s[mi][r];
#pragma unroll
        for (int fj = 0; fj < 4; ++fj) {
          float kf = __uint_as_float((__float_as_uint(acc[mi][fj][r]) & KMASK) |
                                     (unsigned)(codebase + fj * 16));
          float t3 = fminf(M3, fmaxf(M2, kf));
          float t2 = fminf(M2, fmaxf(M1, kf));
          M1 = fminf(M1, kf); M2 = t2; M3 = t3;
        }
        m1s[mi][r] = M1; m2s[mi][r] = M2; m3s[mi][r] = M3;
      }
    }
  }

  // cell = split*32 + wc*16 + col  (64 codes: 16 ct x 4 fj)
  const int cell = split * 32 + wc * 16 + l15;
#pragma unroll
  for (int mi = 0; mi < 4; ++mi) {
#pragma unroll
    for (int r = 0; r < 4; ++r) {
      int token = tb * 128 + wr * 64 + mi * 16 + (lane >> 4) * 4 + r;
      ((float2*)(slot2 + (size_t)token * 256))[cell] = make_float2(m1s[mi][r], m2s[mi][r]);
      slot3[(size_t)token * 128 + cell] = m3s[mi][r];
    }
  }
}

// one wave per token; exact f64 re-rank of margin candidates; writes z_q row.
__global__ void k_select(const float* __restrict__ slot2, const float* __restrict__ slot3,
                         const float* __restrict__ z, const float* __restrict__ w,
                         unsigned int* __restrict__ counts, float* __restrict__ out) {
  const int lane = threadIdx.x & 63;
  const int t = blockIdx.x * 4 + (threadIdx.x >> 6);

  float4 e = *(const float4*)(slot2 + (size_t)t * 256 + lane * 4);  // cells 2l,2l+1 (m1,m2)
  float2 q = *(const float2*)(slot3 + (size_t)t * 128 + lane * 2);  // cells 2l,2l+1 (m3)
  float pk = fminf(e.x, e.z);
#pragma unroll
  for (int m = 1; m < 64; m <<= 1) pk = fminf(pk, __shfl_xor(pk, m));
  const unsigned int mb = __float_as_uint(pk);
  int best = (int)(mb & 0x1FFFu);
  const float thr = __uint_as_float(mb & 0xFFFFE000u) + MARGIN;

  const unsigned int KM = 0xFFFFE000u;
  bool c0 = __uint_as_float(__float_as_uint(e.x) & KM) < thr;
  bool c1 = __uint_as_float(__float_as_uint(e.y) & KM) < thr;
  bool c2 = __uint_as_float(__float_as_uint(e.z) & KM) < thr;
  bool c3 = __uint_as_float(__float_as_uint(e.w) & KM) < thr;
  bool h0 = __uint_as_float(__float_as_uint(q.x) & KM) < thr;  // cell 2l needs full scan
  bool h1 = __uint_as_float(__float_as_uint(q.y) & KM) < thr;  // cell 2l+1
  unsigned long long B0 = __ballot(c0), B1 = __ballot(c1);
  unsigned long long B2 = __ballot(c2), B3 = __ballot(c3);
  unsigned long long H0 = __ballot(h0), H1 = __ballot(h1);
  int nc = __popcll(B0) + __popcll(B1) + __popcll(B2) + __popcll(B3);

  if (nc > 1) {
    const float4* zp = (const float4*)(z + (size_t)t * DIM) + lane * 2;
    float4 za = zp[0], zc = zp[1];
    double bestd = 1e300;
    int besti = NE;

    auto eval = [&](int code) {
      const float4* wp = (const float4*)(w + (size_t)code * DIM) + lane * 2;
      float4 wa = wp[0], wv2 = wp[1];
      double d = (double)wa.x * ((double)wa.x - 2.0 * (double)za.x)
               + (double)wa.y * ((double)wa.y - 2.0 * (double)za.y)
               + (double)wa.z * ((double)wa.z - 2.0 * (double)za.z)
               + (double)wa.w * ((double)wa.w - 2.0 * (double)za.w)
               + (double)wv2.x * ((double)wv2.x - 2.0 * (double)zc.x)
               + (double)wv2.y * ((double)wv2.y - 2.0 * (double)zc.y)
               + (double)wv2.z * ((double)wv2.z - 2.0 * (double)zc.z)
               + (double)wv2.w * ((double)wv2.w - 2.0 * (double)zc.w);
#pragma unroll
      for (int m = 1; m < 64; m <<= 1) d += __shfl_xor(d, m);
      if (d < bestd || (d == bestd && code < besti)) { bestd = d; besti = code; }
    };
    // cell = (split, wc, col): codes sp*2048 + ct*128 + wcc*64 + nf*16 + col
    auto scan_cell = [&](int cid) {
      int sp = cid >> 5, wcc = (cid >> 4) & 1, col = cid & 15;
      int base = sp * 2048 + wcc * 64 + col;
      for (int ctt = 0; ctt < 16; ++ctt)
        for (int nf = 0; nf < 4; ++nf)
          eval(base + ctt * 128 + nf * 16);
    };

    int i0 = (int)(__float_as_uint(e.x) & 0x1FFFu);
    int i1 = (int)(__float_as_uint(e.y) & 0x1FFFu);
    int i2 = (int)(__float_as_uint(e.z) & 0x1FFFu);
    int i3 = (int)(__float_as_uint(e.w) & 0x1FFFu);
    unsigned long long bm;
    bm = __ballot(c0 && !h0); while (bm) { int s = __ffsll(bm) - 1; bm &= bm - 1; eval(__shfl(i0, s)); }
    bm = __ballot(c1 && !h0); while (bm) { int s = __ffsll(bm) - 1; bm &= bm - 1; eval(__shfl(i1, s)); }
    bm = __ballot(c2 && !h1); while (bm) { int s = __ffsll(bm) - 1; bm &= bm - 1; eval(__shfl(i2, s)); }
    bm = __ballot(c3 && !h1); while (bm) { int s = __ffsll(bm) - 1; bm &= bm - 1; eval(__shfl(i3, s)); }
    bm = H0; while (bm) { int s = __ffsll(bm) - 1; bm &= bm - 1; scan_cell(2 * s); }
    bm = H1; while (bm) { int s = __ffsll(bm) - 1; bm &= bm - 1; scan_cell(2 * s + 1); }
    best = besti;
  }
  if (lane == 0) atomicAdd(&counts[best], 1u);
  // write z_q row (gather merged here)
  const float4* wr4 = (const float4*)(w + (size_t)best * DIM);
  float4* o4 = (float4*)(out + (size_t)t * DIM);
  o4[lane]      = wr4[lane];
  o4[lane + 64] = wr4[lane + 64];
}

__global__ void k_perp(const unsigned int* __restrict__ counts, float* __restrict__ out) {
  __shared__ float red[16];
  float s = 0.f;
  for (int k = threadIdx.x; k < NE; k += 1024) {
    float p = (float)counts[k] * (1.0f / (float)NTOK);
    s += p * logf(p + 1e-10f);
  }
#pragma unroll
  for (int m = 1; m < 64; m <<= 1) s += __shfl_xor(s, m);
  int lane = threadIdx.x & 63, wv = threadIdx.x >> 6;
  if (lane == 0) red[wv] = s;
  __syncthreads();
  if (threadIdx.x == 0) {
    float tot = 0.f;
    for (int i = 0; i < 16; ++i) tot += red[i];
    out[(size_t)NTOK * DIM] = expf(-tot);
  }
}

extern "C" void kernel_launch(void* const* d_in, const int* in_sizes, int n_in,
                              void* d_out, int out_size, void* d_ws, size_t ws_size,
                              hipStream_t stream) {
  const float* z = (const float*)d_in[0];
  const float* w = (const float*)d_in[1];
  float* out = (float*)d_out;
  char* ws = (char*)d_ws;

  unsigned char* zb     = (unsigned char*)(ws);
  float*        slot3   = (float*)(ws + 16777216);
  unsigned char* wb     = (unsigned char*)(ws + 33554432);
  float*        cnorm   = (float*)(ws + 41943040);
  float*        slot2   = (float*)(ws + 41975808);
  unsigned int* counts  = (unsigned int*)(ws + 75661312);

  k_prep_z<<<8192, 256, 0, stream>>>(z, (int2*)zb);
  k_prep_w<<<2048, 256, 0, stream>>>(w, (int2*)wb, cnorm);
  k_phase1<<<1024, 256, 0, stream>>>(zb, wb, cnorm, slot2, slot3);
  hipMemsetAsync(counts, 0, NE * sizeof(unsigned int), stream);
  k_select<<<8192, 256, 0, stream>>>(slot2, slot3, z, w, counts, out);
  k_perp<<<1, 1024, 0, stream>>>(counts, out);
}